// Round 3
// baseline (1031.552 us; speedup 1.0000x reference)
//
#include <hip/hip_runtime.h>
#include <stdint.h>

typedef unsigned short u16;
typedef unsigned int   u32;

#define N_NODES  100000
#define N_EDGES  1600000
#define DFEAT    128
#define N_GRAPHS 512

#define NB_N 391      // ceil(N_NODES/256)
#define NB_E 6250     // N_EDGES/256 exactly
#define NBKT 391      // buckets of 256 nodes
#define LBUF 8192     // per-bucket LDS capacity (mean 4096, sigma 64)

typedef float f32x4 __attribute__((ext_vector_type(4)));
typedef short s16x8 __attribute__((ext_vector_type(8)));

__device__ __forceinline__ float bflo(u32 u) { return __uint_as_float(u << 16); }
__device__ __forceinline__ float bfhi(u32 u) { return __uint_as_float(u & 0xffff0000u); }
__device__ __forceinline__ u16 f2bf(float f) {
  u32 u = __float_as_uint(f);
  return (u16)((u + 0x7fffu + ((u >> 16) & 1u)) >> 16);   // RNE
}
__device__ __forceinline__ u32 pack2(float f0, float f1) {
  return (u32)f2bf(f0) | ((u32)f2bf(f1) << 16);
}

// ---------------- int64-vs-int32 detection ----------------
__global__ void detect_k(const int* __restrict__ ei, int* __restrict__ flag) {
  int t = threadIdx.x;
  int v = ei[2 * t + 1];
  unsigned long long m = __ballot(v != 0);
  if (t == 0) *flag = (m == 0ull) ? 1 : 0;
}

__device__ __forceinline__ int ld_src(const int* ei, int m, int e) {
  return m ? ei[2 * e] : ei[e];
}
__device__ __forceinline__ int ld_dst(const int* ei, int m, int e) {
  return m ? ei[2 * (N_EDGES + e)] : ei[N_EDGES + e];
}

// ---------------- setup kernels ----------------

__global__ void init_deg_k(int* __restrict__ deg) {
  int i = blockIdx.x * 256 + threadIdx.x;
  if (i < N_NODES) deg[i] = 1;                 // self-loop
}

__global__ void count_k(const int* __restrict__ ei, const int* __restrict__ flag,
                        int* __restrict__ deg) {
  int e = blockIdx.x * 256 + threadIdx.x;      // grid covers exactly N_EDGES
  int m = *flag;
  atomicAdd(&deg[ld_dst(ei, m, e)], 1);
}

__global__ __launch_bounds__(256) void scan1_k(const int* __restrict__ deg,
                                               int* __restrict__ rowptr,
                                               int* __restrict__ blksum) {
  __shared__ int tmp[256];
  int t = threadIdx.x;
  int gid = blockIdx.x * 256 + t;
  int v = (gid < N_NODES) ? (deg[gid] - 1) : 0;
  tmp[t] = v;
  for (int off = 1; off < 256; off <<= 1) {
    __syncthreads();
    int add = (t >= off) ? tmp[t - off] : 0;
    __syncthreads();
    tmp[t] += add;
  }
  __syncthreads();
  if (gid < N_NODES) rowptr[gid] = tmp[t] - v;   // exclusive within block
  if (t == 255) blksum[blockIdx.x] = tmp[255];
}

__global__ __launch_bounds__(512) void scan2_k(int* __restrict__ blksum) {
  __shared__ int tmp[512];
  int t = threadIdx.x;
  int v = (t < NB_N) ? blksum[t] : 0;
  tmp[t] = v;
  for (int off = 1; off < 512; off <<= 1) {
    __syncthreads();
    int add = (t >= off) ? tmp[t - off] : 0;
    __syncthreads();
    tmp[t] += add;
  }
  __syncthreads();
  if (t < NB_N) blksum[t] = tmp[t] - v;          // exclusive
}

__global__ __launch_bounds__(256) void scan3_k(const int* __restrict__ deg,
                                               int* __restrict__ rowptr,
                                               float* __restrict__ dinv,
                                               int* __restrict__ bcur,
                                               const int* __restrict__ blksum) {
  int gid = blockIdx.x * 256 + threadIdx.x;
  if (gid < N_NODES) {
    int v = rowptr[gid] + blksum[blockIdx.x];
    rowptr[gid] = v;
    if ((gid & 255) == 0) bcur[gid >> 8] = v;    // bucket cursors seeded at CSR bases
    dinv[gid] = rsqrtf((float)deg[gid]);
  }
  if (gid == 0) rowptr[N_NODES] = N_EDGES;
}

// pass B: append src|(dstlocal<<24) into bucket regions (bucket = dst>>8)
__global__ void fillB_k(const int* __restrict__ ei, const int* __restrict__ flag,
                        int* __restrict__ bcur, u32* __restrict__ colpk) {
  int e = blockIdx.x * 256 + threadIdx.x;
  int m = *flag;
  int d = ld_dst(ei, m, e);
  int s = ld_src(ei, m, e);
  int b = d >> 8;
  int pos = atomicAdd(&bcur[b], 1);
  colpk[pos] = (u32)s | ((u32)(d & 255) << 24);
}

// pass C: exact CSR placement within bucket via LDS, coalesced write-out
__global__ __launch_bounds__(256) void fillC_k(const int* __restrict__ rowptr,
                                               const u32* __restrict__ colpk,
                                               int* __restrict__ colarr) {
  __shared__ int lcur[256];
  __shared__ int lbuf[LBUF];
  int t = threadIdx.x;
  int n0 = blockIdx.x * 256;
  int n1 = min(n0 + 256, N_NODES);
  int base = rowptr[n0];
  int end  = rowptr[n1];
  int cnt  = end - base;
  lcur[t] = (n0 + t < N_NODES) ? (rowptr[n0 + t] - base) : cnt;
  __syncthreads();
  for (int i = t; i < cnt; i += 256) {
    u32 v = colpk[base + i];
    int dl = v >> 24;
    int slot = atomicAdd(&lcur[dl], 1);
    if (slot < LBUF) lbuf[slot] = (int)(v & 0x00FFFFFFu);
  }
  __syncthreads();
  for (int i = t; i < cnt; i += 256) colarr[base + i] = lbuf[i];
}

// ---------------- f32 -> bf16 converts ----------------
__global__ void cvt_x_k(const float* __restrict__ X, u32* __restrict__ XB) {
  int i = blockIdx.x * 256 + threadIdx.x;       // grid: 25000 (exact)
  float2 v = ((const float2*)X)[i];
  XB[i] = pack2(v.x, v.y);
}

// W [k][n] f32 -> Wt [n][k] bf16
__global__ void cvt_w_k(const float* __restrict__ W1, const float* __restrict__ W2,
                        const float* __restrict__ W3, u16* __restrict__ T1,
                        u16* __restrict__ T2, u16* __restrict__ T3) {
  const float* W = (blockIdx.x == 0) ? W1 : (blockIdx.x == 1) ? W2 : W3;
  u16* T         = (blockIdx.x == 0) ? T1 : (blockIdx.x == 1) ? T2 : T3;
  for (int i = threadIdx.x; i < DFEAT * DFEAT; i += 256) {
    int n = i >> 7, k = i & 127;
    T[i] = f2bf(W[k * DFEAT + n]);
  }
}

// ---------------- MFMA GEMM: Y[r,:] = bf16((X @ W)[r,:] * dinv[r]) ----------------
#define LP 136   // LDS pitch in ushorts (272B, 16B-aligned rows)

__global__ __launch_bounds__(256, 1) void gemm_scale_k(const u16* __restrict__ X,
                                                       const u16* __restrict__ Wt,
                                                       const float* __restrict__ dinv,
                                                       u16* __restrict__ Y, int nrows) {
  __shared__ u16 sX[64 * LP];
  __shared__ u16 sW[128 * LP];
  int tid = threadIdx.x;
  int r0 = blockIdx.x * 64;

  // stage Wt (128x128 bf16): 2048 x 16B
  for (int c = tid; c < 2048; c += 256) {
    int row = c >> 4, off = (c & 15) * 8;
    *(uint4*)(&sW[row * LP + off]) = *(const uint4*)(Wt + row * DFEAT + off);
  }
  // stage X tile (64x128 bf16), zero-pad OOB rows
  for (int c = tid; c < 1024; c += 256) {
    int row = c >> 4, off = (c & 15) * 8;
    int grow = r0 + row;
    uint4 v;
    if (grow < nrows) v = *(const uint4*)(X + (size_t)grow * DFEAT + off);
    else              v = make_uint4(0, 0, 0, 0);
    *(uint4*)(&sX[row * LP + off]) = v;
  }
  __syncthreads();

  int wave = tid >> 6, lane = tid & 63;
  int q = lane >> 4, r = lane & 15;
  int wr0 = wave * 16;

  f32x4 acc[8];
#pragma unroll
  for (int i = 0; i < 8; i++) acc[i] = (f32x4){0.f, 0.f, 0.f, 0.f};

#pragma unroll
  for (int kk = 0; kk < 4; kk++) {
    int k0 = kk * 32;
    s16x8 a = *(const s16x8*)(&sX[(wr0 + r) * LP + k0 + q * 8]);
#pragma unroll
    for (int nt = 0; nt < 8; nt++) {
      s16x8 b = *(const s16x8*)(&sW[(nt * 16 + r) * LP + k0 + q * 8]);
      acc[nt] = __builtin_amdgcn_mfma_f32_16x16x32_bf16(a, b, acc[nt], 0, 0, 0);
    }
  }

  // epilogue: D row = q*4+i, col = nt*16+r
#pragma unroll
  for (int i = 0; i < 4; i++) {
    int grow = r0 + wr0 + q * 4 + i;
    if (grow < nrows) {
      float dv = dinv[grow];
#pragma unroll
      for (int nt = 0; nt < 8; nt++) {
        Y[(size_t)grow * DFEAT + nt * 16 + r] = f2bf(acc[nt][i] * dv);
      }
    }
  }
}

// ---------------- aggregation (bf16 rows, f32 accumulate) ----------------
// out[i] = act(dinv[i]*(hs[i] + sum_in hs[src]) + b)
__global__ __launch_bounds__(256) void agg_k(const u32* __restrict__ HS,
                                             const float* __restrict__ dinv,
                                             const int* __restrict__ rowptr,
                                             const int* __restrict__ colidx,
                                             const float* __restrict__ bias,
                                             u32* __restrict__ OUT, int do_relu) {
  int node = blockIdx.x * 4 + (threadIdx.x >> 6);   // grid covers exactly N_NODES
  int lane = threadIdx.x & 63;

  int s = rowptr[node], epos = rowptr[node + 1];

  u32 u = HS[(size_t)node * 64 + lane];
  float a0 = bflo(u), a1 = bfhi(u);

  for (int cb = s; cb < epos; cb += 64) {
    int n = min(64, epos - cb);
    int my = (cb + lane < epos) ? colidx[cb + lane] : 0;
    int j = 0;
    for (; j + 4 <= n; j += 4) {
      int i0 = __shfl(my, j), i1 = __shfl(my, j + 1);
      int i2 = __shfl(my, j + 2), i3 = __shfl(my, j + 3);
      u32 v0 = HS[(size_t)i0 * 64 + lane];
      u32 v1 = HS[(size_t)i1 * 64 + lane];
      u32 v2 = HS[(size_t)i2 * 64 + lane];
      u32 v3 = HS[(size_t)i3 * 64 + lane];
      a0 += bflo(v0) + bflo(v1) + bflo(v2) + bflo(v3);
      a1 += bfhi(v0) + bfhi(v1) + bfhi(v2) + bfhi(v3);
    }
    for (; j < n; j++) {
      int i0 = __shfl(my, j);
      u32 v = HS[(size_t)i0 * 64 + lane];
      a0 += bflo(v); a1 += bfhi(v);
    }
  }

  float dv = dinv[node];
  float2 b = ((const float2*)bias)[lane];
  float r0 = a0 * dv + b.x;
  float r1 = a1 * dv + b.y;
  if (do_relu) { r0 = fmaxf(r0, 0.f); r1 = fmaxf(r1, 0.f); }
  OUT[(size_t)node * 64 + lane] = pack2(r0, r1);
}

// ---------------- pooling: mean over sorted batch ranges ----------------
__device__ __forceinline__ int lower_bound_i(const int* a, int n, int key, int shift) {
  int lo = 0, hi = n;
  while (lo < hi) {
    int mid = (lo + hi) >> 1;
    if (a[mid << shift] < key) lo = mid + 1; else hi = mid;
  }
  return lo;
}

__global__ __launch_bounds__(256) void pool_k(const u32* __restrict__ H,
                                              const int* __restrict__ batch,
                                              const int* __restrict__ flag,
                                              float* __restrict__ OUT) {
  int g = blockIdx.x;
  int m = *flag;   // 1 if int64 batch
  int lo = lower_bound_i(batch, N_NODES, g, m);
  int hi = lower_bound_i(batch, N_NODES, g + 1, m);
  int cnt = hi - lo;
  int d2 = threadIdx.x & 63;     // u32 pair index (features 2*d2, 2*d2+1)
  int half = threadIdx.x >> 6;   // 4 row streams
  float a0 = 0.f, a1 = 0.f;
  for (int row = lo + half; row < hi; row += 4) {
    u32 v = H[(size_t)row * 64 + d2];
    a0 += bflo(v); a1 += bfhi(v);
  }
  __shared__ float red0[256], red1[256];
  red0[threadIdx.x] = a0; red1[threadIdx.x] = a1;
  __syncthreads();
  if (threadIdx.x < 64) {
    float s0 = red0[d2] + red0[d2 + 64] + red0[d2 + 128] + red0[d2 + 192];
    float s1 = red1[d2] + red1[d2 + 64] + red1[d2 + 128] + red1[d2 + 192];
    float inv = 1.0f / fmaxf((float)cnt, 1.0f);
    OUT[g * DFEAT + 2 * d2]     = s0 * inv;
    OUT[g * DFEAT + 2 * d2 + 1] = s1 * inv;
  }
}

// ---------------- orchestration ----------------

extern "C" void kernel_launch(void* const* d_in, const int* in_sizes, int n_in,
                              void* d_out, int out_size, void* d_ws, size_t ws_size,
                              hipStream_t stream) {
  const float* x   = (const float*)d_in[0];
  const int* ei    = (const int*)d_in[1];   // [2, E] flat (int32 or int64 -> detected)
  const int* batch = (const int*)d_in[2];
  const float* W1  = (const float*)d_in[3];
  const float* b1  = (const float*)d_in[4];
  const float* W2  = (const float*)d_in[5];
  const float* b2  = (const float*)d_in[6];
  const float* W3  = (const float*)d_in[7];
  const float* b3  = (const float*)d_in[8];
  float* out = (float*)d_out;

  // workspace carve-up (256B aligned)
  char* p = (char*)d_ws;
  size_t off = 0;
  auto carve = [&](size_t bytes) -> void* {
    void* q = p + off;
    off = (off + bytes + 255) & ~(size_t)255;
    return q;
  };
  int*   deg    = (int*)carve(N_NODES * 4);
  int*   rowptr = (int*)carve((N_NODES + 1) * 4);
  int*   blksum = (int*)carve(512 * 4);
  int*   flag   = (int*)carve(256);
  int*   bcur   = (int*)carve(NBKT * 4);
  float* dinv   = (float*)carve(N_NODES * 4);
  u32*   colpk  = (u32*)carve((size_t)N_EDGES * 4);
  int*   colarr = (int*)carve((size_t)N_EDGES * 4);
  u16*   Wt1    = (u16*)carve(DFEAT * DFEAT * 2);
  u16*   Wt2    = (u16*)carve(DFEAT * DFEAT * 2);
  u16*   Wt3    = (u16*)carve(DFEAT * DFEAT * 2);
  u32*   xb     = (u32*)carve((size_t)N_NODES * 64 * 4);
  u32*   bufA   = (u32*)carve((size_t)N_NODES * 64 * 4);
  u32*   bufB   = (u32*)carve((size_t)N_NODES * 64 * 4);
  (void)ws_size;

  // graph structure (recomputed every call; same inputs -> same result)
  detect_k<<<1, 64, 0, stream>>>(ei, flag);
  init_deg_k<<<NB_N, 256, 0, stream>>>(deg);
  count_k<<<NB_E, 256, 0, stream>>>(ei, flag, deg);
  scan1_k<<<NB_N, 256, 0, stream>>>(deg, rowptr, blksum);
  scan2_k<<<1, 512, 0, stream>>>(blksum);
  scan3_k<<<NB_N, 256, 0, stream>>>(deg, rowptr, dinv, bcur, blksum);
  fillB_k<<<NB_E, 256, 0, stream>>>(ei, flag, bcur, colpk);
  fillC_k<<<NBKT, 256, 0, stream>>>(rowptr, colpk, colarr);

  // bf16 conversions
  cvt_x_k<<<25000, 256, 0, stream>>>(x, xb);
  cvt_w_k<<<3, 256, 0, stream>>>(W1, W2, W3, Wt1, Wt2, Wt3);

  const int GB = (N_NODES + 63) / 64;   // 1563
  const int AB = N_NODES / 4;           // 25000

  // layer 1
  gemm_scale_k<<<GB, 256, 0, stream>>>((const u16*)xb, Wt1, dinv, (u16*)bufA, N_NODES);
  agg_k<<<AB, 256, 0, stream>>>(bufA, dinv, rowptr, colarr, b1, bufB, 1);
  // layer 2
  gemm_scale_k<<<GB, 256, 0, stream>>>((const u16*)bufB, Wt2, dinv, (u16*)bufA, N_NODES);
  agg_k<<<AB, 256, 0, stream>>>(bufA, dinv, rowptr, colarr, b2, bufB, 1);
  // layer 3 (no relu)
  gemm_scale_k<<<GB, 256, 0, stream>>>((const u16*)bufB, Wt3, dinv, (u16*)bufA, N_NODES);
  agg_k<<<AB, 256, 0, stream>>>(bufA, dinv, rowptr, colarr, b3, bufB, 0);
  // pooling
  pool_k<<<N_GRAPHS, 256, 0, stream>>>(bufB, batch, flag, out);
}

// Round 5
// 424.583 us; speedup vs baseline: 2.4296x; 2.4296x over previous
//
#include <hip/hip_runtime.h>
#include <stdint.h>

typedef unsigned short u16;
typedef unsigned int   u32;

#define N_NODES  100000
#define N_EDGES  1600000
#define DFEAT    128
#define N_GRAPHS 512

#define NBKT   391    // buckets of 256 nodes (ceil(N/256))
#define NBLK_E 782    // ceil(N_EDGES/2048)
#define LBUF   8192   // per-bucket capacity (mean 4096, sigma ~64)

typedef float f32x4 __attribute__((ext_vector_type(4)));
typedef short s16x8 __attribute__((ext_vector_type(8)));

__device__ __forceinline__ float bflo(u32 u) { return __uint_as_float(u << 16); }
__device__ __forceinline__ float bfhi(u32 u) { return __uint_as_float(u & 0xffff0000u); }
__device__ __forceinline__ u16 f2bf(float f) {
  u32 u = __float_as_uint(f);
  return (u16)((u + 0x7fffu + ((u >> 16) & 1u)) >> 16);   // RNE
}
__device__ __forceinline__ u32 pack2(float f0, float f1) {
  return (u32)f2bf(f0) | ((u32)f2bf(f1) << 16);
}

// ---------------- int64-vs-int32 detection ----------------
__global__ void detect_k(const int* __restrict__ ei, int* __restrict__ flag) {
  int t = threadIdx.x;
  int v = ei[2 * t + 1];
  unsigned long long m = __ballot(v != 0);
  if (t == 0) *flag = (m == 0ull) ? 1 : 0;
}

__device__ __forceinline__ int ld_src(const int* ei, int m, int e) {
  return m ? ei[2 * e] : ei[e];
}
__device__ __forceinline__ int ld_dst(const int* ei, int m, int e) {
  return m ? ei[2 * (N_EDGES + e)] : ei[N_EDGES + e];
}

// ---------------- graph build: atomic-free counting sort by dst ----------------

// pass A: per-block bucket histogram (LDS atomics only)
__global__ __launch_bounds__(256) void histA_k(const int* __restrict__ ei,
                                               const int* __restrict__ flag,
                                               int* __restrict__ ghist) {
  __shared__ int hist[NBKT];
  int t = threadIdx.x, b = blockIdx.x;
  for (int i = t; i < NBKT; i += 256) hist[i] = 0;
  __syncthreads();
  int m = *flag;
  int e0 = b * 2048;
#pragma unroll
  for (int p = 0; p < 8; p++) {
    int e = e0 + p * 256 + t;
    if (e < N_EDGES) atomicAdd(&hist[ld_dst(ei, m, e) >> 8], 1);
  }
  __syncthreads();
  for (int i = t; i < NBKT; i += 256) ghist[b * NBKT + i] = hist[i];
}

// pass B1: per bucket k, exclusive scan of ghist[:,k] over blocks (in place) + total
__global__ __launch_bounds__(256) void scanB1_k(int* __restrict__ ghist,
                                                int* __restrict__ gtot) {
  __shared__ int a[1024];
  __shared__ int ts[256];
  int t = threadIdx.x, k = blockIdx.x;
  for (int i = t; i < 1024; i += 256) a[i] = (i < NBLK_E) ? ghist[i * NBKT + k] : 0;
  __syncthreads();
  int b4 = t * 4;
  int x0 = a[b4], x1 = a[b4 + 1], x2 = a[b4 + 2], x3 = a[b4 + 3];
  int tot = x0 + x1 + x2 + x3;
  ts[t] = tot;
  for (int off = 1; off < 256; off <<= 1) {
    __syncthreads(); int add = (t >= off) ? ts[t - off] : 0;
    __syncthreads(); ts[t] += add;
  }
  __syncthreads();
  int excl = ts[t] - tot;
  a[b4] = excl; a[b4 + 1] = excl + x0; a[b4 + 2] = excl + x0 + x1; a[b4 + 3] = excl + x0 + x1 + x2;
  __syncthreads();
  for (int i = t; i < NBLK_E; i += 256) ghist[i * NBKT + k] = a[i];
  if (t == 255) gtot[k] = ts[255];
}

// pass B2: exclusive scan of bucket totals -> bucket bases
__global__ __launch_bounds__(512) void scanB2_k(const int* __restrict__ gtot,
                                                int* __restrict__ bbase) {
  __shared__ int tmp[512];
  int t = threadIdx.x;
  int v = (t < NBKT) ? gtot[t] : 0;
  tmp[t] = v;
  for (int off = 1; off < 512; off <<= 1) {
    __syncthreads(); int add = (t >= off) ? tmp[t - off] : 0;
    __syncthreads(); tmp[t] += add;
  }
  __syncthreads();
  if (t < NBKT) bbase[t] = tmp[t] - v;
  if (t == 0) bbase[NBKT] = N_EDGES;
}

// pass C: place edges into bucket regions (LDS cursors, disjoint ranges per block)
__global__ __launch_bounds__(256) void scatterC_k(const int* __restrict__ ei,
                                                  const int* __restrict__ flag,
                                                  const int* __restrict__ obase,
                                                  const int* __restrict__ bbase,
                                                  u32* __restrict__ colpk) {
  __shared__ int cur[NBKT];
  int t = threadIdx.x, b = blockIdx.x;
  for (int i = t; i < NBKT; i += 256) cur[i] = bbase[i] + obase[b * NBKT + i];
  __syncthreads();
  int m = *flag;
  int e0 = b * 2048;
#pragma unroll
  for (int p = 0; p < 8; p++) {
    int e = e0 + p * 256 + t;
    if (e < N_EDGES) {
      int d = ld_dst(ei, m, e);
      int s = ld_src(ei, m, e);
      int pos = atomicAdd(&cur[d >> 8], 1);
      colpk[pos] = (u32)s | ((u32)(d & 255) << 24);
    }
  }
}

// pass D: per bucket -> node degrees (LDS hist), rowptr, dinv, exact CSR placement
__global__ __launch_bounds__(256) void fillD_k(const int* __restrict__ bbase,
                                               const u32* __restrict__ colpk,
                                               int* __restrict__ colarr,
                                               int* __restrict__ rowptr,
                                               float* __restrict__ dinv) {
  __shared__ int hist[256];
  __shared__ int cur[256];
  __shared__ int lbuf[LBUF];
  int t = threadIdx.x, b = blockIdx.x;
  int base = bbase[b], end = bbase[b + 1], cnt = end - base;
  hist[t] = 0;
  __syncthreads();
  for (int i = t; i < cnt; i += 256) atomicAdd(&hist[colpk[base + i] >> 24], 1);
  __syncthreads();
  int c = hist[t];
  cur[t] = c;
  for (int off = 1; off < 256; off <<= 1) {
    __syncthreads(); int add = (t >= off) ? cur[t - off] : 0;
    __syncthreads(); cur[t] += add;
  }
  __syncthreads();
  int excl = cur[t] - c;
  int node = b * 256 + t;
  if (node < N_NODES) {
    rowptr[node] = base + excl;
    dinv[node] = rsqrtf((float)(c + 1));      // +1 self-loop
  }
  if (b == NBKT - 1 && t == 0) rowptr[N_NODES] = N_EDGES;
  __syncthreads();
  cur[t] = excl;
  __syncthreads();
  for (int i = t; i < cnt; i += 256) {
    u32 v = colpk[base + i];
    int slot = atomicAdd(&cur[v >> 24], 1);
    if (slot < LBUF) lbuf[slot] = (int)(v & 0x00FFFFFFu);
  }
  __syncthreads();
  for (int i = t; i < cnt; i += 256) colarr[base + i] = lbuf[i];
}

// ---------------- f32 -> bf16 converts ----------------
__global__ void cvt_x_k(const float* __restrict__ X, u32* __restrict__ XB) {
  int i = blockIdx.x * 256 + threadIdx.x;       // grid: 25000 (exact)
  float2 v = ((const float2*)X)[i];
  XB[i] = pack2(v.x, v.y);
}

// W [k][n] f32 -> Wt [n][k] bf16
__global__ void cvt_w_k(const float* __restrict__ W1, const float* __restrict__ W2,
                        const float* __restrict__ W3, u16* __restrict__ T1,
                        u16* __restrict__ T2, u16* __restrict__ T3) {
  const float* W = (blockIdx.x == 0) ? W1 : (blockIdx.x == 1) ? W2 : W3;
  u16* T         = (blockIdx.x == 0) ? T1 : (blockIdx.x == 1) ? T2 : T3;
  for (int i = threadIdx.x; i < DFEAT * DFEAT; i += 256) {
    int n = i >> 7, k = i & 127;
    T[i] = f2bf(W[k * DFEAT + n]);
  }
}

// ---------------- MFMA GEMM: Y[r,:] = bf16((X @ W)[r,:] * dinv[r]) ----------------
#define LP 136   // LDS pitch in ushorts (272B, 16B-aligned rows)

__global__ __launch_bounds__(256, 1) void gemm_scale_k(const u16* __restrict__ X,
                                                       const u16* __restrict__ Wt,
                                                       const float* __restrict__ dinv,
                                                       u16* __restrict__ Y, int nrows) {
  __shared__ u16 sX[64 * LP];
  __shared__ u16 sW[128 * LP];
  int tid = threadIdx.x;
  int r0 = blockIdx.x * 64;

  for (int c = tid; c < 2048; c += 256) {
    int row = c >> 4, off = (c & 15) * 8;
    *(uint4*)(&sW[row * LP + off]) = *(const uint4*)(Wt + row * DFEAT + off);
  }
  for (int c = tid; c < 1024; c += 256) {
    int row = c >> 4, off = (c & 15) * 8;
    int grow = r0 + row;
    uint4 v;
    if (grow < nrows) v = *(const uint4*)(X + (size_t)grow * DFEAT + off);
    else              v = make_uint4(0, 0, 0, 0);
    *(uint4*)(&sX[row * LP + off]) = v;
  }
  __syncthreads();

  int wave = tid >> 6, lane = tid & 63;
  int q = lane >> 4, r = lane & 15;
  int wr0 = wave * 16;

  f32x4 acc[8];
#pragma unroll
  for (int i = 0; i < 8; i++) acc[i] = (f32x4){0.f, 0.f, 0.f, 0.f};

#pragma unroll
  for (int kk = 0; kk < 4; kk++) {
    int k0 = kk * 32;
    s16x8 a = *(const s16x8*)(&sX[(wr0 + r) * LP + k0 + q * 8]);
#pragma unroll
    for (int nt = 0; nt < 8; nt++) {
      s16x8 b = *(const s16x8*)(&sW[(nt * 16 + r) * LP + k0 + q * 8]);
      acc[nt] = __builtin_amdgcn_mfma_f32_16x16x32_bf16(a, b, acc[nt], 0, 0, 0);
    }
  }

#pragma unroll
  for (int i = 0; i < 4; i++) {
    int grow = r0 + wr0 + q * 4 + i;
    if (grow < nrows) {
      float dv = dinv[grow];
#pragma unroll
      for (int nt = 0; nt < 8; nt++) {
        Y[(size_t)grow * DFEAT + nt * 16 + r] = f2bf(acc[nt][i] * dv);
      }
    }
  }
}

// ---------------- aggregation (bf16 rows, f32 accumulate) ----------------
// node per 16-lane group; lane owns 16B feature chunk -> uint4 gathers, 4 rows
// in flight per VMEM instruction, coalesced 4KB stores per block.
struct Acc8 {
  float a0, a1, a2, a3, a4, a5, a6, a7;
  __device__ __forceinline__ void add(uint4 v) {
    a0 += bflo(v.x); a1 += bfhi(v.x); a2 += bflo(v.y); a3 += bfhi(v.y);
    a4 += bflo(v.z); a5 += bfhi(v.z); a6 += bflo(v.w); a7 += bfhi(v.w);
  }
};

__global__ __launch_bounds__(256) void agg_k(const u32* __restrict__ HS,
                                             const float* __restrict__ dinv,
                                             const int* __restrict__ rowptr,
                                             const int* __restrict__ colidx,
                                             const float* __restrict__ bias,
                                             u32* __restrict__ OUT, int do_relu) {
  int t = threadIdx.x;
  int node = blockIdx.x * 16 + (t >> 4);   // grid 6250 -> exactly N_NODES
  int fp = t & 15;

  int s = rowptr[node], e = rowptr[node + 1];

  Acc8 A;
  uint4 v = *(const uint4*)(HS + (size_t)node * 64 + fp * 4);   // self row
  A.a0 = bflo(v.x); A.a1 = bfhi(v.x); A.a2 = bflo(v.y); A.a3 = bfhi(v.y);
  A.a4 = bflo(v.z); A.a5 = bfhi(v.z); A.a6 = bflo(v.w); A.a7 = bfhi(v.w);

  int j = s;
  for (; j + 4 <= e; j += 4) {
    int i0 = colidx[j], i1 = colidx[j + 1], i2 = colidx[j + 2], i3 = colidx[j + 3];
    uint4 w0 = *(const uint4*)(HS + (size_t)i0 * 64 + fp * 4);
    uint4 w1 = *(const uint4*)(HS + (size_t)i1 * 64 + fp * 4);
    uint4 w2 = *(const uint4*)(HS + (size_t)i2 * 64 + fp * 4);
    uint4 w3 = *(const uint4*)(HS + (size_t)i3 * 64 + fp * 4);
    A.add(w0); A.add(w1); A.add(w2); A.add(w3);
  }
  for (; j < e; j++) {
    int i0 = colidx[j];
    uint4 w0 = *(const uint4*)(HS + (size_t)i0 * 64 + fp * 4);
    A.add(w0);
  }

  float dv = dinv[node];
  float4 b0 = *(const float4*)(bias + fp * 8);
  float4 b1 = *(const float4*)(bias + fp * 8 + 4);
  float r0 = A.a0 * dv + b0.x, r1 = A.a1 * dv + b0.y;
  float r2 = A.a2 * dv + b0.z, r3 = A.a3 * dv + b0.w;
  float r4 = A.a4 * dv + b1.x, r5 = A.a5 * dv + b1.y;
  float r6 = A.a6 * dv + b1.z, r7 = A.a7 * dv + b1.w;
  if (do_relu) {
    r0 = fmaxf(r0, 0.f); r1 = fmaxf(r1, 0.f); r2 = fmaxf(r2, 0.f); r3 = fmaxf(r3, 0.f);
    r4 = fmaxf(r4, 0.f); r5 = fmaxf(r5, 0.f); r6 = fmaxf(r6, 0.f); r7 = fmaxf(r7, 0.f);
  }
  uint4 o;
  o.x = pack2(r0, r1); o.y = pack2(r2, r3); o.z = pack2(r4, r5); o.w = pack2(r6, r7);
  *(uint4*)(OUT + (size_t)node * 64 + fp * 4) = o;
}

// ---------------- pooling: mean over sorted batch ranges ----------------
__device__ __forceinline__ int lower_bound_i(const int* a, int n, int key, int shift) {
  int lo = 0, hi = n;
  while (lo < hi) {
    int mid = (lo + hi) >> 1;
    if (a[mid << shift] < key) lo = mid + 1; else hi = mid;
  }
  return lo;
}

__global__ __launch_bounds__(256) void pool_k(const u32* __restrict__ H,
                                              const int* __restrict__ batch,
                                              const int* __restrict__ flag,
                                              float* __restrict__ OUT) {
  int g = blockIdx.x;
  int m = *flag;   // 1 if int64 batch
  int lo = lower_bound_i(batch, N_NODES, g, m);
  int hi = lower_bound_i(batch, N_NODES, g + 1, m);
  int cnt = hi - lo;
  int d2 = threadIdx.x & 63;
  int half = threadIdx.x >> 6;
  float a0 = 0.f, a1 = 0.f;
  for (int row = lo + half; row < hi; row += 4) {
    u32 v = H[(size_t)row * 64 + d2];
    a0 += bflo(v); a1 += bfhi(v);
  }
  __shared__ float red0[256], red1[256];
  red0[threadIdx.x] = a0; red1[threadIdx.x] = a1;
  __syncthreads();
  if (threadIdx.x < 64) {
    float s0 = red0[d2] + red0[d2 + 64] + red0[d2 + 128] + red0[d2 + 192];
    float s1 = red1[d2] + red1[d2 + 64] + red1[d2 + 128] + red1[d2 + 192];
    float inv = 1.0f / fmaxf((float)cnt, 1.0f);
    OUT[g * DFEAT + 2 * d2]     = s0 * inv;
    OUT[g * DFEAT + 2 * d2 + 1] = s1 * inv;
  }
}

// ---------------- orchestration ----------------

extern "C" void kernel_launch(void* const* d_in, const int* in_sizes, int n_in,
                              void* d_out, int out_size, void* d_ws, size_t ws_size,
                              hipStream_t stream) {
  const float* x   = (const float*)d_in[0];
  const int* ei    = (const int*)d_in[1];
  const int* batch = (const int*)d_in[2];
  const float* W1  = (const float*)d_in[3];
  const float* b1  = (const float*)d_in[4];
  const float* W2  = (const float*)d_in[5];
  const float* b2  = (const float*)d_in[6];
  const float* W3  = (const float*)d_in[7];
  const float* b3  = (const float*)d_in[8];
  float* out = (float*)d_out;

  char* p = (char*)d_ws;
  size_t off = 0;
  auto carve = [&](size_t bytes) -> void* {
    void* q = p + off;
    off = (off + bytes + 255) & ~(size_t)255;
    return q;
  };
  int*   flag   = (int*)carve(256);
  int*   ghist  = (int*)carve((size_t)NBLK_E * NBKT * 4);   // becomes obase in-place
  int*   gtot   = (int*)carve(NBKT * 4);
  int*   bbase  = (int*)carve((NBKT + 1) * 4);
  int*   rowptr = (int*)carve((N_NODES + 1) * 4);
  float* dinv   = (float*)carve(N_NODES * 4);
  u32*   colpk  = (u32*)carve((size_t)N_EDGES * 4);
  int*   colarr = (int*)carve((size_t)N_EDGES * 4);
  u16*   Wt1    = (u16*)carve(DFEAT * DFEAT * 2);
  u16*   Wt2    = (u16*)carve(DFEAT * DFEAT * 2);
  u16*   Wt3    = (u16*)carve(DFEAT * DFEAT * 2);
  u32*   xb     = (u32*)carve((size_t)N_NODES * 64 * 4);
  u32*   bufA   = (u32*)carve((size_t)N_NODES * 64 * 4);
  u32*   bufB   = (u32*)carve((size_t)N_NODES * 64 * 4);
  (void)ws_size;

  detect_k<<<1, 64, 0, stream>>>(ei, flag);
  histA_k<<<NBLK_E, 256, 0, stream>>>(ei, flag, ghist);
  scanB1_k<<<NBKT, 256, 0, stream>>>(ghist, gtot);
  scanB2_k<<<1, 512, 0, stream>>>(gtot, bbase);
  scatterC_k<<<NBLK_E, 256, 0, stream>>>(ei, flag, ghist, bbase, colpk);
  fillD_k<<<NBKT, 256, 0, stream>>>(bbase, colpk, colarr, rowptr, dinv);

  cvt_x_k<<<25000, 256, 0, stream>>>(x, xb);
  cvt_w_k<<<3, 256, 0, stream>>>(W1, W2, W3, Wt1, Wt2, Wt3);

  const int GB = (N_NODES + 63) / 64;   // 1563
  const int AB = N_NODES / 16;          // 6250

  gemm_scale_k<<<GB, 256, 0, stream>>>((const u16*)xb, Wt1, dinv, (u16*)bufA, N_NODES);
  agg_k<<<AB, 256, 0, stream>>>(bufA, dinv, rowptr, colarr, b1, bufB, 1);
  gemm_scale_k<<<GB, 256, 0, stream>>>((const u16*)bufB, Wt2, dinv, (u16*)bufA, N_NODES);
  agg_k<<<AB, 256, 0, stream>>>(bufA, dinv, rowptr, colarr, b2, bufB, 1);
  gemm_scale_k<<<GB, 256, 0, stream>>>((const u16*)bufB, Wt3, dinv, (u16*)bufA, N_NODES);
  agg_k<<<AB, 256, 0, stream>>>(bufA, dinv, rowptr, colarr, b3, bufB, 0);
  pool_k<<<N_GRAPHS, 256, 0, stream>>>(bufB, batch, flag, out);
}

// Round 6
// 412.919 us; speedup vs baseline: 2.4982x; 1.0282x over previous
//
#include <hip/hip_runtime.h>
#include <stdint.h>

typedef unsigned short u16;
typedef unsigned int   u32;

#define N_NODES  100000
#define N_EDGES  1600000
#define DFEAT    128
#define N_GRAPHS 512

#define NBKT   391    // buckets of 256 nodes (ceil(N/256))
#define NBLK_E 782    // ceil(N_EDGES/2048)
#define LBUF   8192   // per-bucket capacity (mean 4096, sigma ~64)

typedef float f32x4 __attribute__((ext_vector_type(4)));
typedef short s16x8 __attribute__((ext_vector_type(8)));

__device__ __forceinline__ float bflo(u32 u) { return __uint_as_float(u << 16); }
__device__ __forceinline__ float bfhi(u32 u) { return __uint_as_float(u & 0xffff0000u); }
__device__ __forceinline__ u16 f2bf(float f) {
  u32 u = __float_as_uint(f);
  return (u16)((u + 0x7fffu + ((u >> 16) & 1u)) >> 16);   // RNE
}
__device__ __forceinline__ u32 pack2(float f0, float f1) {
  return (u32)f2bf(f0) | ((u32)f2bf(f1) << 16);
}

__device__ __forceinline__ int ld_src(const int* ei, int m, int e) {
  return m ? ei[2 * e] : ei[e];
}
__device__ __forceinline__ int ld_dst(const int* ei, int m, int e) {
  return m ? ei[2 * (N_EDGES + e)] : ei[N_EDGES + e];
}

// ---------------- prep: int64 detect (block 0) + W transpose/convert (blocks 1-3) ----
__global__ __launch_bounds__(256) void prep_k(const int* __restrict__ ei, int* __restrict__ flag,
                                              const float* __restrict__ W1, const float* __restrict__ W2,
                                              const float* __restrict__ W3, u16* __restrict__ T1,
                                              u16* __restrict__ T2, u16* __restrict__ T3) {
  int t = threadIdx.x;
  if (blockIdx.x == 0) {
    if (t < 64) {
      int v = ei[2 * t + 1];
      unsigned long long m = __ballot(v != 0);
      if (t == 0) *flag = (m == 0ull) ? 1 : 0;
    }
    return;
  }
  const float* W = (blockIdx.x == 1) ? W1 : (blockIdx.x == 2) ? W2 : W3;
  u16* T         = (blockIdx.x == 1) ? T1 : (blockIdx.x == 2) ? T2 : T3;
  for (int i = t; i < DFEAT * DFEAT; i += 256) {
    int n = i >> 7, k = i & 127;
    T[i] = f2bf(W[k * DFEAT + n]);
  }
}

// ---------------- graph build: atomic-free counting sort by dst ----------------

__global__ __launch_bounds__(256) void histA_k(const int* __restrict__ ei,
                                               const int* __restrict__ flag,
                                               int* __restrict__ ghist) {
  __shared__ int hist[NBKT];
  int t = threadIdx.x, b = blockIdx.x;
  for (int i = t; i < NBKT; i += 256) hist[i] = 0;
  __syncthreads();
  int m = *flag;
  int e0 = b * 2048;
#pragma unroll
  for (int p = 0; p < 8; p++) {
    int e = e0 + p * 256 + t;
    if (e < N_EDGES) atomicAdd(&hist[ld_dst(ei, m, e) >> 8], 1);
  }
  __syncthreads();
  for (int i = t; i < NBKT; i += 256) ghist[b * NBKT + i] = hist[i];
}

__global__ __launch_bounds__(256) void scanB1_k(int* __restrict__ ghist,
                                                int* __restrict__ gtot) {
  __shared__ int a[1024];
  __shared__ int ts[256];
  int t = threadIdx.x, k = blockIdx.x;
  for (int i = t; i < 1024; i += 256) a[i] = (i < NBLK_E) ? ghist[i * NBKT + k] : 0;
  __syncthreads();
  int b4 = t * 4;
  int x0 = a[b4], x1 = a[b4 + 1], x2 = a[b4 + 2], x3 = a[b4 + 3];
  int tot = x0 + x1 + x2 + x3;
  ts[t] = tot;
  for (int off = 1; off < 256; off <<= 1) {
    __syncthreads(); int add = (t >= off) ? ts[t - off] : 0;
    __syncthreads(); ts[t] += add;
  }
  __syncthreads();
  int excl = ts[t] - tot;
  a[b4] = excl; a[b4 + 1] = excl + x0; a[b4 + 2] = excl + x0 + x1; a[b4 + 3] = excl + x0 + x1 + x2;
  __syncthreads();
  for (int i = t; i < NBLK_E; i += 256) ghist[i * NBKT + k] = a[i];
  if (t == 255) gtot[k] = ts[255];
}

__global__ __launch_bounds__(512) void scanB2_k(const int* __restrict__ gtot,
                                                int* __restrict__ bbase) {
  __shared__ int tmp[512];
  int t = threadIdx.x;
  int v = (t < NBKT) ? gtot[t] : 0;
  tmp[t] = v;
  for (int off = 1; off < 512; off <<= 1) {
    __syncthreads(); int add = (t >= off) ? tmp[t - off] : 0;
    __syncthreads(); tmp[t] += add;
  }
  __syncthreads();
  if (t < NBKT) bbase[t] = tmp[t] - v;
  if (t == 0) bbase[NBKT] = N_EDGES;
}

__global__ __launch_bounds__(256) void scatterC_k(const int* __restrict__ ei,
                                                  const int* __restrict__ flag,
                                                  const int* __restrict__ obase,
                                                  const int* __restrict__ bbase,
                                                  u32* __restrict__ colpk) {
  __shared__ int cur[NBKT];
  int t = threadIdx.x, b = blockIdx.x;
  for (int i = t; i < NBKT; i += 256) cur[i] = bbase[i] + obase[b * NBKT + i];
  __syncthreads();
  int m = *flag;
  int e0 = b * 2048;
#pragma unroll
  for (int p = 0; p < 8; p++) {
    int e = e0 + p * 256 + t;
    if (e < N_EDGES) {
      int d = ld_dst(ei, m, e);
      int s = ld_src(ei, m, e);
      int pos = atomicAdd(&cur[d >> 8], 1);
      colpk[pos] = (u32)s | ((u32)(d & 255) << 24);
    }
  }
}

__global__ __launch_bounds__(256) void fillD_k(const int* __restrict__ bbase,
                                               const u32* __restrict__ colpk,
                                               int* __restrict__ colarr,
                                               int* __restrict__ rowptr,
                                               float* __restrict__ dinv) {
  __shared__ int hist[256];
  __shared__ int cur[256];
  __shared__ int lbuf[LBUF];
  int t = threadIdx.x, b = blockIdx.x;
  int base = bbase[b], end = bbase[b + 1], cnt = end - base;
  hist[t] = 0;
  __syncthreads();
  for (int i = t; i < cnt; i += 256) atomicAdd(&hist[colpk[base + i] >> 24], 1);
  __syncthreads();
  int c = hist[t];
  cur[t] = c;
  for (int off = 1; off < 256; off <<= 1) {
    __syncthreads(); int add = (t >= off) ? cur[t - off] : 0;
    __syncthreads(); cur[t] += add;
  }
  __syncthreads();
  int excl = cur[t] - c;
  int node = b * 256 + t;
  if (node < N_NODES) {
    rowptr[node] = base + excl;
    dinv[node] = rsqrtf((float)(c + 1));      // +1 self-loop
  }
  if (b == NBKT - 1 && t == 0) rowptr[N_NODES] = N_EDGES;
  __syncthreads();
  cur[t] = excl;
  __syncthreads();
  for (int i = t; i < cnt; i += 256) {
    u32 v = colpk[base + i];
    int slot = atomicAdd(&cur[v >> 24], 1);
    if (slot < LBUF) lbuf[slot] = (int)(v & 0x00FFFFFFu);
  }
  __syncthreads();
  for (int i = t; i < cnt; i += 256) colarr[base + i] = lbuf[i];
}

// ---------------- MFMA GEMM: Y[r,:] = bf16((X @ W)[r,:] * dinv[r]) ----------------
// 128x128 tile, 4 waves (each: 2 M-tiles x 8 N-tiles). X input either bf16 or f32
// (f32 path converts during LDS staging -> fuses the cvt_x kernel into gemm1).
#define LP 136   // LDS pitch in ushorts (272B, 16B-aligned rows)

__global__ __launch_bounds__(256, 1) void gemm_scale_k(const void* __restrict__ Xv,
                                                       int x_is_f32,
                                                       const u16* __restrict__ Wt,
                                                       const float* __restrict__ dinv,
                                                       u16* __restrict__ Y, int nrows) {
  __shared__ u16 sX[128 * LP];
  __shared__ u16 sW[128 * LP];
  int tid = threadIdx.x;
  int r0 = blockIdx.x * 128;

  for (int c = tid; c < 2048; c += 256) {
    int row = c >> 4, off = (c & 15) * 8;
    *(uint4*)(&sW[row * LP + off]) = *(const uint4*)(Wt + row * DFEAT + off);
  }
  if (x_is_f32) {
    const float* Xf = (const float*)Xv;
    for (int c = tid; c < 2048; c += 256) {
      int row = c >> 4, off = (c & 15) * 8;
      int grow = r0 + row;
      uint4 o = make_uint4(0, 0, 0, 0);
      if (grow < nrows) {
        const float* px = Xf + (size_t)grow * DFEAT + off;
        float4 v0 = *(const float4*)px;
        float4 v1 = *(const float4*)(px + 4);
        o.x = pack2(v0.x, v0.y); o.y = pack2(v0.z, v0.w);
        o.z = pack2(v1.x, v1.y); o.w = pack2(v1.z, v1.w);
      }
      *(uint4*)(&sX[row * LP + off]) = o;
    }
  } else {
    const u16* Xb = (const u16*)Xv;
    for (int c = tid; c < 2048; c += 256) {
      int row = c >> 4, off = (c & 15) * 8;
      int grow = r0 + row;
      uint4 v = make_uint4(0, 0, 0, 0);
      if (grow < nrows) v = *(const uint4*)(Xb + (size_t)grow * DFEAT + off);
      *(uint4*)(&sX[row * LP + off]) = v;
    }
  }
  __syncthreads();

  int wave = tid >> 6, lane = tid & 63;
  int q = lane >> 4, r = lane & 15;
  int wr0 = wave * 32;

  f32x4 acc[2][8];
#pragma unroll
  for (int m = 0; m < 2; m++)
#pragma unroll
    for (int i = 0; i < 8; i++) acc[m][i] = (f32x4){0.f, 0.f, 0.f, 0.f};

#pragma unroll
  for (int kk = 0; kk < 4; kk++) {
    int k0 = kk * 32;
    s16x8 a0 = *(const s16x8*)(&sX[(wr0 + r) * LP + k0 + q * 8]);
    s16x8 a1 = *(const s16x8*)(&sX[(wr0 + 16 + r) * LP + k0 + q * 8]);
#pragma unroll
    for (int nt = 0; nt < 8; nt++) {
      s16x8 b = *(const s16x8*)(&sW[(nt * 16 + r) * LP + k0 + q * 8]);
      acc[0][nt] = __builtin_amdgcn_mfma_f32_16x16x32_bf16(a0, b, acc[0][nt], 0, 0, 0);
      acc[1][nt] = __builtin_amdgcn_mfma_f32_16x16x32_bf16(a1, b, acc[1][nt], 0, 0, 0);
    }
  }

#pragma unroll
  for (int m = 0; m < 2; m++) {
#pragma unroll
    for (int i = 0; i < 4; i++) {
      int grow = r0 + wr0 + m * 16 + q * 4 + i;
      if (grow < nrows) {
        float dv = dinv[grow];
#pragma unroll
        for (int nt = 0; nt < 8; nt++) {
          Y[(size_t)grow * DFEAT + nt * 16 + r] = f2bf(acc[m][nt][i] * dv);
        }
      }
    }
  }
}

// ---------------- aggregation (bf16 rows, f32 accumulate) ----------------
// node per 16-lane group; lane owns 16B chunk (uint4 gathers). Column indices
// prefetched 16-at-a-time with one coalesced load + shfl broadcast; 8 gathers
// in flight per lane.
struct Acc8 {
  float a0, a1, a2, a3, a4, a5, a6, a7;
  __device__ __forceinline__ void add(uint4 v) {
    a0 += bflo(v.x); a1 += bfhi(v.x); a2 += bflo(v.y); a3 += bfhi(v.y);
    a4 += bflo(v.z); a5 += bfhi(v.z); a6 += bflo(v.w); a7 += bfhi(v.w);
  }
};

__global__ __launch_bounds__(256) void agg_k(const u32* __restrict__ HS,
                                             const float* __restrict__ dinv,
                                             const int* __restrict__ rowptr,
                                             const int* __restrict__ colidx,
                                             const float* __restrict__ bias,
                                             u32* __restrict__ OUT, int do_relu) {
  int t = threadIdx.x;
  int node = blockIdx.x * 16 + (t >> 4);   // grid 6250 -> exactly N_NODES
  int fp = t & 15;

  int s = rowptr[node], e = rowptr[node + 1];

  Acc8 A;
  uint4 v = *(const uint4*)(HS + (size_t)node * 64 + fp * 4);   // self row
  A.a0 = bflo(v.x); A.a1 = bfhi(v.x); A.a2 = bflo(v.y); A.a3 = bfhi(v.y);
  A.a4 = bflo(v.z); A.a5 = bfhi(v.z); A.a6 = bflo(v.w); A.a7 = bfhi(v.w);

  for (int w = s; w < e; w += 16) {
    int c = (w + fp < e) ? colidx[w + fp] : 0;   // 1 coalesced load per 16 edges
    int n = min(16, e - w);
    int j = 0;
    for (; j + 8 <= n; j += 8) {
      int i0 = __shfl(c, j, 16),     i1 = __shfl(c, j + 1, 16);
      int i2 = __shfl(c, j + 2, 16), i3 = __shfl(c, j + 3, 16);
      int i4 = __shfl(c, j + 4, 16), i5 = __shfl(c, j + 5, 16);
      int i6 = __shfl(c, j + 6, 16), i7 = __shfl(c, j + 7, 16);
      uint4 w0 = *(const uint4*)(HS + (size_t)i0 * 64 + fp * 4);
      uint4 w1 = *(const uint4*)(HS + (size_t)i1 * 64 + fp * 4);
      uint4 w2 = *(const uint4*)(HS + (size_t)i2 * 64 + fp * 4);
      uint4 w3 = *(const uint4*)(HS + (size_t)i3 * 64 + fp * 4);
      uint4 w4 = *(const uint4*)(HS + (size_t)i4 * 64 + fp * 4);
      uint4 w5 = *(const uint4*)(HS + (size_t)i5 * 64 + fp * 4);
      uint4 w6 = *(const uint4*)(HS + (size_t)i6 * 64 + fp * 4);
      uint4 w7 = *(const uint4*)(HS + (size_t)i7 * 64 + fp * 4);
      A.add(w0); A.add(w1); A.add(w2); A.add(w3);
      A.add(w4); A.add(w5); A.add(w6); A.add(w7);
    }
    for (; j + 4 <= n; j += 4) {
      int i0 = __shfl(c, j, 16),     i1 = __shfl(c, j + 1, 16);
      int i2 = __shfl(c, j + 2, 16), i3 = __shfl(c, j + 3, 16);
      uint4 w0 = *(const uint4*)(HS + (size_t)i0 * 64 + fp * 4);
      uint4 w1 = *(const uint4*)(HS + (size_t)i1 * 64 + fp * 4);
      uint4 w2 = *(const uint4*)(HS + (size_t)i2 * 64 + fp * 4);
      uint4 w3 = *(const uint4*)(HS + (size_t)i3 * 64 + fp * 4);
      A.add(w0); A.add(w1); A.add(w2); A.add(w3);
    }
    for (; j < n; j++) {
      int i0 = __shfl(c, j, 16);
      uint4 w0 = *(const uint4*)(HS + (size_t)i0 * 64 + fp * 4);
      A.add(w0);
    }
  }

  float dv = dinv[node];
  float4 b0 = *(const float4*)(bias + fp * 8);
  float4 b1 = *(const float4*)(bias + fp * 8 + 4);
  float r0 = A.a0 * dv + b0.x, r1 = A.a1 * dv + b0.y;
  float r2 = A.a2 * dv + b0.z, r3 = A.a3 * dv + b0.w;
  float r4 = A.a4 * dv + b1.x, r5 = A.a5 * dv + b1.y;
  float r6 = A.a6 * dv + b1.z, r7 = A.a7 * dv + b1.w;
  if (do_relu) {
    r0 = fmaxf(r0, 0.f); r1 = fmaxf(r1, 0.f); r2 = fmaxf(r2, 0.f); r3 = fmaxf(r3, 0.f);
    r4 = fmaxf(r4, 0.f); r5 = fmaxf(r5, 0.f); r6 = fmaxf(r6, 0.f); r7 = fmaxf(r7, 0.f);
  }
  uint4 o;
  o.x = pack2(r0, r1); o.y = pack2(r2, r3); o.z = pack2(r4, r5); o.w = pack2(r6, r7);
  *(uint4*)(OUT + (size_t)node * 64 + fp * 4) = o;
}

// ---------------- pooling: mean over sorted batch ranges ----------------
__device__ __forceinline__ int lower_bound_i(const int* a, int n, int key, int shift) {
  int lo = 0, hi = n;
  while (lo < hi) {
    int mid = (lo + hi) >> 1;
    if (a[mid << shift] < key) lo = mid + 1; else hi = mid;
  }
  return lo;
}

__global__ __launch_bounds__(256) void pool_k(const u32* __restrict__ H,
                                              const int* __restrict__ batch,
                                              const int* __restrict__ flag,
                                              float* __restrict__ OUT) {
  int g = blockIdx.x;
  int m = *flag;   // 1 if int64 batch
  int lo = lower_bound_i(batch, N_NODES, g, m);
  int hi = lower_bound_i(batch, N_NODES, g + 1, m);
  int cnt = hi - lo;
  int d2 = threadIdx.x & 63;
  int half = threadIdx.x >> 6;
  float a0 = 0.f, a1 = 0.f;
  for (int row = lo + half; row < hi; row += 4) {
    u32 v = H[(size_t)row * 64 + d2];
    a0 += bflo(v); a1 += bfhi(v);
  }
  __shared__ float red0[256], red1[256];
  red0[threadIdx.x] = a0; red1[threadIdx.x] = a1;
  __syncthreads();
  if (threadIdx.x < 64) {
    float s0 = red0[d2] + red0[d2 + 64] + red0[d2 + 128] + red0[d2 + 192];
    float s1 = red1[d2] + red1[d2 + 64] + red1[d2 + 128] + red1[d2 + 192];
    float inv = 1.0f / fmaxf((float)cnt, 1.0f);
    OUT[g * DFEAT + 2 * d2]     = s0 * inv;
    OUT[g * DFEAT + 2 * d2 + 1] = s1 * inv;
  }
}

// ---------------- orchestration ----------------

extern "C" void kernel_launch(void* const* d_in, const int* in_sizes, int n_in,
                              void* d_out, int out_size, void* d_ws, size_t ws_size,
                              hipStream_t stream) {
  const float* x   = (const float*)d_in[0];
  const int* ei    = (const int*)d_in[1];
  const int* batch = (const int*)d_in[2];
  const float* W1  = (const float*)d_in[3];
  const float* b1  = (const float*)d_in[4];
  const float* W2  = (const float*)d_in[5];
  const float* b2  = (const float*)d_in[6];
  const float* W3  = (const float*)d_in[7];
  const float* b3  = (const float*)d_in[8];
  float* out = (float*)d_out;

  char* p = (char*)d_ws;
  size_t off = 0;
  auto carve = [&](size_t bytes) -> void* {
    void* q = p + off;
    off = (off + bytes + 255) & ~(size_t)255;
    return q;
  };
  int*   flag   = (int*)carve(256);
  int*   ghist  = (int*)carve((size_t)NBLK_E * NBKT * 4);   // becomes obase in-place
  int*   gtot   = (int*)carve(NBKT * 4);
  int*   bbase  = (int*)carve((NBKT + 1) * 4);
  int*   rowptr = (int*)carve((N_NODES + 1) * 4);
  float* dinv   = (float*)carve(N_NODES * 4);
  u32*   colpk  = (u32*)carve((size_t)N_EDGES * 4);
  int*   colarr = (int*)carve((size_t)N_EDGES * 4);
  u16*   Wt1    = (u16*)carve(DFEAT * DFEAT * 2);
  u16*   Wt2    = (u16*)carve(DFEAT * DFEAT * 2);
  u16*   Wt3    = (u16*)carve(DFEAT * DFEAT * 2);
  u32*   bufA   = (u32*)carve((size_t)N_NODES * 64 * 4);
  u32*   bufB   = (u32*)carve((size_t)N_NODES * 64 * 4);
  (void)ws_size;

  prep_k<<<4, 256, 0, stream>>>(ei, flag, W1, W2, W3, Wt1, Wt2, Wt3);
  histA_k<<<NBLK_E, 256, 0, stream>>>(ei, flag, ghist);
  scanB1_k<<<NBKT, 256, 0, stream>>>(ghist, gtot);
  scanB2_k<<<1, 512, 0, stream>>>(gtot, bbase);
  scatterC_k<<<NBLK_E, 256, 0, stream>>>(ei, flag, ghist, bbase, colpk);
  fillD_k<<<NBKT, 256, 0, stream>>>(bbase, colpk, colarr, rowptr, dinv);

  const int GB = (N_NODES + 127) / 128;   // 782
  const int AB = N_NODES / 16;            // 6250

  gemm_scale_k<<<GB, 256, 0, stream>>>((const void*)x, 1, Wt1, dinv, (u16*)bufA, N_NODES);
  agg_k<<<AB, 256, 0, stream>>>(bufA, dinv, rowptr, colarr, b1, bufB, 1);
  gemm_scale_k<<<GB, 256, 0, stream>>>((const void*)bufB, 0, Wt2, dinv, (u16*)bufA, N_NODES);
  agg_k<<<AB, 256, 0, stream>>>(bufA, dinv, rowptr, colarr, b2, bufB, 1);
  gemm_scale_k<<<GB, 256, 0, stream>>>((const void*)bufB, 0, Wt3, dinv, (u16*)bufA, N_NODES);
  agg_k<<<AB, 256, 0, stream>>>(bufA, dinv, rowptr, colarr, b3, bufB, 0);
  pool_k<<<N_GRAPHS, 256, 0, stream>>>(bufB, batch, flag, out);
}

// Round 7
// 411.173 us; speedup vs baseline: 2.5088x; 1.0042x over previous
//
#include <hip/hip_runtime.h>
#include <stdint.h>

typedef unsigned short u16;
typedef unsigned int   u32;

#define N_NODES  100000
#define N_EDGES  1600000
#define DFEAT    128
#define N_GRAPHS 512

#define NBKT   391    // buckets of 256 nodes (ceil(N/256))
#define NBLK_E 782    // ceil(N_EDGES/2048)
#define LBUF   8192   // per-bucket capacity (mean 4096, sigma ~64)

typedef float f32x4 __attribute__((ext_vector_type(4)));
typedef short s16x8 __attribute__((ext_vector_type(8)));

__device__ __forceinline__ float bflo(u32 u) { return __uint_as_float(u << 16); }
__device__ __forceinline__ float bfhi(u32 u) { return __uint_as_float(u & 0xffff0000u); }
__device__ __forceinline__ u16 f2bf(float f) {
  u32 u = __float_as_uint(f);
  return (u16)((u + 0x7fffu + ((u >> 16) & 1u)) >> 16);   // RNE
}
__device__ __forceinline__ u32 pack2(float f0, float f1) {
  return (u32)f2bf(f0) | ((u32)f2bf(f1) << 16);
}

__device__ __forceinline__ int ld_src(const int* ei, int m, int e) {
  return m ? ei[2 * e] : ei[e];
}
__device__ __forceinline__ int ld_dst(const int* ei, int m, int e) {
  return m ? ei[2 * (N_EDGES + e)] : ei[N_EDGES + e];
}

// ---------------- prep: int64 detect (block 0) + W transpose/convert (blocks 1-3) ----
__global__ __launch_bounds__(256) void prep_k(const int* __restrict__ ei, int* __restrict__ flag,
                                              const float* __restrict__ W1, const float* __restrict__ W2,
                                              const float* __restrict__ W3, u16* __restrict__ T1,
                                              u16* __restrict__ T2, u16* __restrict__ T3) {
  int t = threadIdx.x;
  if (blockIdx.x == 0) {
    if (t < 64) {
      int v = ei[2 * t + 1];
      unsigned long long m = __ballot(v != 0);
      if (t == 0) *flag = (m == 0ull) ? 1 : 0;
    }
    return;
  }
  const float* W = (blockIdx.x == 1) ? W1 : (blockIdx.x == 2) ? W2 : W3;
  u16* T         = (blockIdx.x == 1) ? T1 : (blockIdx.x == 2) ? T2 : T3;
  for (int i = t; i < DFEAT * DFEAT; i += 256) {
    int n = i >> 7, k = i & 127;
    T[i] = f2bf(W[k * DFEAT + n]);
  }
}

// ---------------- graph build: atomic-free counting sort by dst ----------------

__global__ __launch_bounds__(256) void histA_k(const int* __restrict__ ei,
                                               const int* __restrict__ flag,
                                               int* __restrict__ ghist) {
  __shared__ int hist[NBKT];
  int t = threadIdx.x, b = blockIdx.x;
  for (int i = t; i < NBKT; i += 256) hist[i] = 0;
  __syncthreads();
  int m = *flag;
  int e0 = b * 2048;
#pragma unroll
  for (int p = 0; p < 8; p++) {
    int e = e0 + p * 256 + t;
    if (e < N_EDGES) atomicAdd(&hist[ld_dst(ei, m, e) >> 8], 1);
  }
  __syncthreads();
  for (int i = t; i < NBKT; i += 256) ghist[b * NBKT + i] = hist[i];
}

__global__ __launch_bounds__(256) void scanB1_k(int* __restrict__ ghist,
                                                int* __restrict__ gtot) {
  __shared__ int a[1024];
  __shared__ int ts[256];
  int t = threadIdx.x, k = blockIdx.x;
  for (int i = t; i < 1024; i += 256) a[i] = (i < NBLK_E) ? ghist[i * NBKT + k] : 0;
  __syncthreads();
  int b4 = t * 4;
  int x0 = a[b4], x1 = a[b4 + 1], x2 = a[b4 + 2], x3 = a[b4 + 3];
  int tot = x0 + x1 + x2 + x3;
  ts[t] = tot;
  for (int off = 1; off < 256; off <<= 1) {
    __syncthreads(); int add = (t >= off) ? ts[t - off] : 0;
    __syncthreads(); ts[t] += add;
  }
  __syncthreads();
  int excl = ts[t] - tot;
  a[b4] = excl; a[b4 + 1] = excl + x0; a[b4 + 2] = excl + x0 + x1; a[b4 + 3] = excl + x0 + x1 + x2;
  __syncthreads();
  for (int i = t; i < NBLK_E; i += 256) ghist[i * NBKT + k] = a[i];
  if (t == 255) gtot[k] = ts[255];
}

// in-block exclusive scan of gtot[NBKT] -> bb[NBKT+1] (256 threads, two passes)
__device__ __forceinline__ void scan_gtot_block(const int* __restrict__ gtot,
                                                int* bb, int* sc) {
  int t = threadIdx.x;
  int v0 = gtot[t];                       // t in [0,256), NBKT>256
  sc[t] = v0;
  for (int off = 1; off < 256; off <<= 1) {
    __syncthreads(); int add = (t >= off) ? sc[t - off] : 0;
    __syncthreads(); sc[t] += add;
  }
  __syncthreads();
  bb[t] = sc[t] - v0;
  int base256 = sc[255];
  __syncthreads();
  int v1 = (t < NBKT - 256) ? gtot[256 + t] : 0;
  sc[t] = v1;
  for (int off = 1; off < 256; off <<= 1) {
    __syncthreads(); int add = (t >= off) ? sc[t - off] : 0;
    __syncthreads(); sc[t] += add;
  }
  __syncthreads();
  if (t < NBKT - 256) bb[256 + t] = base256 + sc[t] - v1;
  if (t == 0) bb[NBKT] = N_EDGES;
  __syncthreads();
}

__global__ __launch_bounds__(256) void scatterC_k(const int* __restrict__ ei,
                                                  const int* __restrict__ flag,
                                                  const int* __restrict__ obase,
                                                  const int* __restrict__ gtot,
                                                  u32* __restrict__ colpk) {
  __shared__ int cur[NBKT];
  __shared__ int bb[NBKT + 1];
  __shared__ int sc[256];
  int t = threadIdx.x, b = blockIdx.x;
  scan_gtot_block(gtot, bb, sc);
  for (int i = t; i < NBKT; i += 256) cur[i] = bb[i] + obase[b * NBKT + i];
  __syncthreads();
  int m = *flag;
  int e0 = b * 2048;
#pragma unroll
  for (int p = 0; p < 8; p++) {
    int e = e0 + p * 256 + t;
    if (e < N_EDGES) {
      int d = ld_dst(ei, m, e);
      int s = ld_src(ei, m, e);
      int pos = atomicAdd(&cur[d >> 8], 1);
      colpk[pos] = (u32)s | ((u32)(d & 255) << 24);
    }
  }
}

__global__ __launch_bounds__(256) void fillD_k(const int* __restrict__ gtot,
                                               const u32* __restrict__ colpk,
                                               int* __restrict__ colarr,
                                               int* __restrict__ rowptr,
                                               float* __restrict__ dinv) {
  __shared__ int hist[256];
  __shared__ int cur[256];
  __shared__ int lbuf[LBUF];
  __shared__ int bb[NBKT + 1];
  __shared__ int sc[256];
  int t = threadIdx.x, b = blockIdx.x;
  scan_gtot_block(gtot, bb, sc);
  int base = bb[b], end = bb[b + 1], cnt = end - base;
  hist[t] = 0;
  __syncthreads();
  for (int i = t; i < cnt; i += 256) atomicAdd(&hist[colpk[base + i] >> 24], 1);
  __syncthreads();
  int c = hist[t];
  cur[t] = c;
  for (int off = 1; off < 256; off <<= 1) {
    __syncthreads(); int add = (t >= off) ? cur[t - off] : 0;
    __syncthreads(); cur[t] += add;
  }
  __syncthreads();
  int excl = cur[t] - c;
  int node = b * 256 + t;
  if (node < N_NODES) {
    rowptr[node] = base + excl;
    dinv[node] = rsqrtf((float)(c + 1));      // +1 self-loop
  }
  if (b == NBKT - 1 && t == 0) rowptr[N_NODES] = N_EDGES;
  __syncthreads();
  cur[t] = excl;
  __syncthreads();
  for (int i = t; i < cnt; i += 256) {
    u32 v = colpk[base + i];
    int slot = atomicAdd(&cur[v >> 24], 1);
    if (slot < LBUF) lbuf[slot] = (int)(v & 0x00FFFFFFu);
  }
  __syncthreads();
  for (int i = t; i < cnt; i += 256) colarr[base + i] = lbuf[i];
}

// ---------------- MFMA GEMM: Y[r,:] = bf16((X @ W)[r,:] * dinv[r]) ----------------
#define LP 136   // LDS pitch in ushorts (272B, 16B-aligned rows)

__global__ __launch_bounds__(256, 1) void gemm_scale_k(const float* __restrict__ Xf,
                                                       const u16* __restrict__ Wt,
                                                       const float* __restrict__ dinv,
                                                       u16* __restrict__ Y, int nrows) {
  __shared__ u16 sX[128 * LP];
  __shared__ u16 sW[128 * LP];
  int tid = threadIdx.x;
  int r0 = blockIdx.x * 128;

  for (int c = tid; c < 2048; c += 256) {
    int row = c >> 4, off = (c & 15) * 8;
    *(uint4*)(&sW[row * LP + off]) = *(const uint4*)(Wt + row * DFEAT + off);
  }
  for (int c = tid; c < 2048; c += 256) {
    int row = c >> 4, off = (c & 15) * 8;
    int grow = r0 + row;
    uint4 o = make_uint4(0, 0, 0, 0);
    if (grow < nrows) {
      const float* px = Xf + (size_t)grow * DFEAT + off;
      float4 v0 = *(const float4*)px;
      float4 v1 = *(const float4*)(px + 4);
      o.x = pack2(v0.x, v0.y); o.y = pack2(v0.z, v0.w);
      o.z = pack2(v1.x, v1.y); o.w = pack2(v1.z, v1.w);
    }
    *(uint4*)(&sX[row * LP + off]) = o;
  }
  __syncthreads();

  int wave = tid >> 6, lane = tid & 63;
  int q = lane >> 4, r = lane & 15;
  int wr0 = wave * 32;

  f32x4 acc[2][8];
#pragma unroll
  for (int m = 0; m < 2; m++)
#pragma unroll
    for (int i = 0; i < 8; i++) acc[m][i] = (f32x4){0.f, 0.f, 0.f, 0.f};

#pragma unroll
  for (int kk = 0; kk < 4; kk++) {
    int k0 = kk * 32;
    s16x8 a0 = *(const s16x8*)(&sX[(wr0 + r) * LP + k0 + q * 8]);
    s16x8 a1 = *(const s16x8*)(&sX[(wr0 + 16 + r) * LP + k0 + q * 8]);
#pragma unroll
    for (int nt = 0; nt < 8; nt++) {
      s16x8 b = *(const s16x8*)(&sW[(nt * 16 + r) * LP + k0 + q * 8]);
      acc[0][nt] = __builtin_amdgcn_mfma_f32_16x16x32_bf16(a0, b, acc[0][nt], 0, 0, 0);
      acc[1][nt] = __builtin_amdgcn_mfma_f32_16x16x32_bf16(a1, b, acc[1][nt], 0, 0, 0);
    }
  }

#pragma unroll
  for (int m = 0; m < 2; m++) {
#pragma unroll
    for (int i = 0; i < 4; i++) {
      int grow = r0 + wr0 + m * 16 + q * 4 + i;
      if (grow < nrows) {
        float dv = dinv[grow];
#pragma unroll
        for (int nt = 0; nt < 8; nt++) {
          Y[(size_t)grow * DFEAT + nt * 16 + r] = f2bf(acc[m][nt][i] * dv);
        }
      }
    }
  }
}

// ---------------- gather-accumulate helper ----------------
struct Acc8 {
  float a0, a1, a2, a3, a4, a5, a6, a7;
  __device__ __forceinline__ void add(uint4 v) {
    a0 += bflo(v.x); a1 += bfhi(v.x); a2 += bflo(v.y); a3 += bfhi(v.y);
    a4 += bflo(v.z); a5 += bfhi(v.z); a6 += bflo(v.w); a7 += bfhi(v.w);
  }
};

__device__ __forceinline__ Acc8 gather_row(const u32* __restrict__ HS,
                                           const int* __restrict__ rowptr,
                                           const int* __restrict__ colidx,
                                           int node, int fp) {
  int s = rowptr[node], e = rowptr[node + 1];
  Acc8 A;
  uint4 v = *(const uint4*)(HS + (size_t)node * 64 + fp * 4);   // self row
  A.a0 = bflo(v.x); A.a1 = bfhi(v.x); A.a2 = bflo(v.y); A.a3 = bfhi(v.y);
  A.a4 = bflo(v.z); A.a5 = bfhi(v.z); A.a6 = bflo(v.w); A.a7 = bfhi(v.w);
  for (int w = s; w < e; w += 16) {
    int c = (w + fp < e) ? colidx[w + fp] : 0;
    int n = min(16, e - w);
    int j = 0;
    for (; j + 8 <= n; j += 8) {
      int i0 = __shfl(c, j, 16),     i1 = __shfl(c, j + 1, 16);
      int i2 = __shfl(c, j + 2, 16), i3 = __shfl(c, j + 3, 16);
      int i4 = __shfl(c, j + 4, 16), i5 = __shfl(c, j + 5, 16);
      int i6 = __shfl(c, j + 6, 16), i7 = __shfl(c, j + 7, 16);
      uint4 w0 = *(const uint4*)(HS + (size_t)i0 * 64 + fp * 4);
      uint4 w1 = *(const uint4*)(HS + (size_t)i1 * 64 + fp * 4);
      uint4 w2 = *(const uint4*)(HS + (size_t)i2 * 64 + fp * 4);
      uint4 w3 = *(const uint4*)(HS + (size_t)i3 * 64 + fp * 4);
      uint4 w4 = *(const uint4*)(HS + (size_t)i4 * 64 + fp * 4);
      uint4 w5 = *(const uint4*)(HS + (size_t)i5 * 64 + fp * 4);
      uint4 w6 = *(const uint4*)(HS + (size_t)i6 * 64 + fp * 4);
      uint4 w7 = *(const uint4*)(HS + (size_t)i7 * 64 + fp * 4);
      A.add(w0); A.add(w1); A.add(w2); A.add(w3);
      A.add(w4); A.add(w5); A.add(w6); A.add(w7);
    }
    for (; j + 4 <= n; j += 4) {
      int i0 = __shfl(c, j, 16),     i1 = __shfl(c, j + 1, 16);
      int i2 = __shfl(c, j + 2, 16), i3 = __shfl(c, j + 3, 16);
      uint4 w0 = *(const uint4*)(HS + (size_t)i0 * 64 + fp * 4);
      uint4 w1 = *(const uint4*)(HS + (size_t)i1 * 64 + fp * 4);
      uint4 w2 = *(const uint4*)(HS + (size_t)i2 * 64 + fp * 4);
      uint4 w3 = *(const uint4*)(HS + (size_t)i3 * 64 + fp * 4);
      A.add(w0); A.add(w1); A.add(w2); A.add(w3);
    }
    for (; j < n; j++) {
      int i0 = __shfl(c, j, 16);
      uint4 w0 = *(const uint4*)(HS + (size_t)i0 * 64 + fp * 4);
      A.add(w0);
    }
  }
  return A;
}

// ---------------- fused agg(layer i epilogue) + gemm(layer i+1) ----------------
// 512 threads, 64 dst rows per block. Gather phase: 32 groups x 16 lanes, 2 rows
// each -> relu(dinv*sum + bias) -> bf16 into sX. MFMA phase: 8 waves, 4Mx8N tiles.
__global__ __launch_bounds__(512) void agg_gemm_k(const u32* __restrict__ HS,
                                                  const float* __restrict__ dinv,
                                                  const int* __restrict__ rowptr,
                                                  const int* __restrict__ colidx,
                                                  const float* __restrict__ bias,
                                                  const u16* __restrict__ Wt,
                                                  u16* __restrict__ Y) {
  __shared__ u16 sX[64 * LP];
  __shared__ u16 sW[128 * LP];
  int tid = threadIdx.x;
  int r0 = blockIdx.x * 64;

  // stage W: 2048 uint4, 4 per thread
  for (int c = tid; c < 2048; c += 512) {
    int row = c >> 4, off = (c & 15) * 8;
    *(uint4*)(&sW[row * LP + off]) = *(const uint4*)(Wt + row * DFEAT + off);
  }

  // gather phase
  int g = tid >> 4, fp = tid & 15;
  float4 b0 = *(const float4*)(bias + fp * 8);
  float4 b1 = *(const float4*)(bias + fp * 8 + 4);
#pragma unroll
  for (int j = 0; j < 2; j++) {
    int lrow = g * 2 + j;
    int node = r0 + lrow;
    uint4 o = make_uint4(0, 0, 0, 0);
    if (node < N_NODES) {
      Acc8 A = gather_row(HS, rowptr, colidx, node, fp);
      float dv = dinv[node];
      float r0f = fmaxf(A.a0 * dv + b0.x, 0.f), r1f = fmaxf(A.a1 * dv + b0.y, 0.f);
      float r2f = fmaxf(A.a2 * dv + b0.z, 0.f), r3f = fmaxf(A.a3 * dv + b0.w, 0.f);
      float r4f = fmaxf(A.a4 * dv + b1.x, 0.f), r5f = fmaxf(A.a5 * dv + b1.y, 0.f);
      float r6f = fmaxf(A.a6 * dv + b1.z, 0.f), r7f = fmaxf(A.a7 * dv + b1.w, 0.f);
      o.x = pack2(r0f, r1f); o.y = pack2(r2f, r3f);
      o.z = pack2(r4f, r5f); o.w = pack2(r6f, r7f);
    }
    *(uint4*)(&sX[lrow * LP + fp * 8]) = o;
  }
  __syncthreads();

  // MFMA phase
  int wave = tid >> 6, lane = tid & 63;
  int q = lane >> 4, r = lane & 15;
  int mt = wave >> 1;            // 0..3
  int nt0 = (wave & 1) * 4;      // 0 or 4

  f32x4 acc[4];
#pragma unroll
  for (int i = 0; i < 4; i++) acc[i] = (f32x4){0.f, 0.f, 0.f, 0.f};

#pragma unroll
  for (int kk = 0; kk < 4; kk++) {
    int k0 = kk * 32;
    s16x8 a = *(const s16x8*)(&sX[(mt * 16 + r) * LP + k0 + q * 8]);
#pragma unroll
    for (int nt = 0; nt < 4; nt++) {
      s16x8 b = *(const s16x8*)(&sW[((nt0 + nt) * 16 + r) * LP + k0 + q * 8]);
      acc[nt] = __builtin_amdgcn_mfma_f32_16x16x32_bf16(a, b, acc[nt], 0, 0, 0);
    }
  }

#pragma unroll
  for (int i = 0; i < 4; i++) {
    int grow = r0 + mt * 16 + q * 4 + i;
    if (grow < N_NODES) {
      float dv = dinv[grow];
#pragma unroll
      for (int nt = 0; nt < 4; nt++) {
        Y[(size_t)grow * DFEAT + (nt0 + nt) * 16 + r] = f2bf(acc[nt][i] * dv);
      }
    }
  }
}

// ---------------- standalone aggregation (layer 3 epilogue) ----------------
__global__ __launch_bounds__(256) void agg_k(const u32* __restrict__ HS,
                                             const float* __restrict__ dinv,
                                             const int* __restrict__ rowptr,
                                             const int* __restrict__ colidx,
                                             const float* __restrict__ bias,
                                             u32* __restrict__ OUT, int do_relu) {
  int t = threadIdx.x;
  int node = blockIdx.x * 16 + (t >> 4);   // grid 6250 -> exactly N_NODES
  int fp = t & 15;

  Acc8 A = gather_row(HS, rowptr, colidx, node, fp);

  float dv = dinv[node];
  float4 b0 = *(const float4*)(bias + fp * 8);
  float4 b1 = *(const float4*)(bias + fp * 8 + 4);
  float r0 = A.a0 * dv + b0.x, r1 = A.a1 * dv + b0.y;
  float r2 = A.a2 * dv + b0.z, r3 = A.a3 * dv + b0.w;
  float r4 = A.a4 * dv + b1.x, r5 = A.a5 * dv + b1.y;
  float r6 = A.a6 * dv + b1.z, r7 = A.a7 * dv + b1.w;
  if (do_relu) {
    r0 = fmaxf(r0, 0.f); r1 = fmaxf(r1, 0.f); r2 = fmaxf(r2, 0.f); r3 = fmaxf(r3, 0.f);
    r4 = fmaxf(r4, 0.f); r5 = fmaxf(r5, 0.f); r6 = fmaxf(r6, 0.f); r7 = fmaxf(r7, 0.f);
  }
  uint4 o;
  o.x = pack2(r0, r1); o.y = pack2(r2, r3); o.z = pack2(r4, r5); o.w = pack2(r6, r7);
  *(uint4*)(OUT + (size_t)node * 64 + fp * 4) = o;
}

// ---------------- pooling: mean over sorted batch ranges ----------------
__device__ __forceinline__ int lower_bound_i(const int* a, int n, int key, int shift) {
  int lo = 0, hi = n;
  while (lo < hi) {
    int mid = (lo + hi) >> 1;
    if (a[mid << shift] < key) lo = mid + 1; else hi = mid;
  }
  return lo;
}

__global__ __launch_bounds__(256) void pool_k(const u32* __restrict__ H,
                                              const int* __restrict__ batch,
                                              const int* __restrict__ flag,
                                              float* __restrict__ OUT) {
  int g = blockIdx.x;
  int m = *flag;   // 1 if int64 batch
  int lo = lower_bound_i(batch, N_NODES, g, m);
  int hi = lower_bound_i(batch, N_NODES, g + 1, m);
  int cnt = hi - lo;
  int d2 = threadIdx.x & 63;
  int half = threadIdx.x >> 6;
  float a0 = 0.f, a1 = 0.f;
  for (int row = lo + half; row < hi; row += 4) {
    u32 v = H[(size_t)row * 64 + d2];
    a0 += bflo(v); a1 += bfhi(v);
  }
  __shared__ float red0[256], red1[256];
  red0[threadIdx.x] = a0; red1[threadIdx.x] = a1;
  __syncthreads();
  if (threadIdx.x < 64) {
    float s0 = red0[d2] + red0[d2 + 64] + red0[d2 + 128] + red0[d2 + 192];
    float s1 = red1[d2] + red1[d2 + 64] + red1[d2 + 128] + red1[d2 + 192];
    float inv = 1.0f / fmaxf((float)cnt, 1.0f);
    OUT[g * DFEAT + 2 * d2]     = s0 * inv;
    OUT[g * DFEAT + 2 * d2 + 1] = s1 * inv;
  }
}

// ---------------- orchestration ----------------

extern "C" void kernel_launch(void* const* d_in, const int* in_sizes, int n_in,
                              void* d_out, int out_size, void* d_ws, size_t ws_size,
                              hipStream_t stream) {
  const float* x   = (const float*)d_in[0];
  const int* ei    = (const int*)d_in[1];
  const int* batch = (const int*)d_in[2];
  const float* W1  = (const float*)d_in[3];
  const float* b1  = (const float*)d_in[4];
  const float* W2  = (const float*)d_in[5];
  const float* b2  = (const float*)d_in[6];
  const float* W3  = (const float*)d_in[7];
  const float* b3  = (const float*)d_in[8];
  float* out = (float*)d_out;

  char* p = (char*)d_ws;
  size_t off = 0;
  auto carve = [&](size_t bytes) -> void* {
    void* q = p + off;
    off = (off + bytes + 255) & ~(size_t)255;
    return q;
  };
  int*   flag   = (int*)carve(256);
  int*   ghist  = (int*)carve((size_t)NBLK_E * NBKT * 4);   // becomes obase in-place
  int*   gtot   = (int*)carve(NBKT * 4);
  int*   rowptr = (int*)carve((N_NODES + 1) * 4);
  float* dinv   = (float*)carve(N_NODES * 4);
  u32*   colpk  = (u32*)carve((size_t)N_EDGES * 4);
  int*   colarr = (int*)carve((size_t)N_EDGES * 4);
  u16*   Wt1    = (u16*)carve(DFEAT * DFEAT * 2);
  u16*   Wt2    = (u16*)carve(DFEAT * DFEAT * 2);
  u16*   Wt3    = (u16*)carve(DFEAT * DFEAT * 2);
  u32*   bufA   = (u32*)carve((size_t)N_NODES * 64 * 4);
  u32*   bufB   = (u32*)carve((size_t)N_NODES * 64 * 4);
  (void)ws_size;

  prep_k<<<4, 256, 0, stream>>>(ei, flag, W1, W2, W3, Wt1, Wt2, Wt3);
  histA_k<<<NBLK_E, 256, 0, stream>>>(ei, flag, ghist);
  scanB1_k<<<NBKT, 256, 0, stream>>>(ghist, gtot);
  scatterC_k<<<NBLK_E, 256, 0, stream>>>(ei, flag, ghist, gtot, colpk);
  fillD_k<<<NBKT, 256, 0, stream>>>(gtot, colpk, colarr, rowptr, dinv);

  const int GB = (N_NODES + 127) / 128;   // 782
  const int FB = (N_NODES + 63) / 64;     // 1563
  const int AB = N_NODES / 16;            // 6250

  // layer 1 GEMM (f32 x converted during staging)
  gemm_scale_k<<<GB, 256, 0, stream>>>(x, Wt1, dinv, (u16*)bufA, N_NODES);
  // agg(L1 epilogue) fused with GEMM(L2)
  agg_gemm_k<<<FB, 512, 0, stream>>>(bufA, dinv, rowptr, colarr, b1, Wt2, (u16*)bufB);
  // agg(L2 epilogue) fused with GEMM(L3)
  agg_gemm_k<<<FB, 512, 0, stream>>>(bufB, dinv, rowptr, colarr, b2, Wt3, (u16*)bufA);
  // final aggregation (no relu)
  agg_k<<<AB, 256, 0, stream>>>(bufA, dinv, rowptr, colarr, b3, bufB, 0);
  pool_k<<<N_GRAPHS, 256, 0, stream>>>(bufB, batch, flag, out);
}

// Round 8
// 405.887 us; speedup vs baseline: 2.5415x; 1.0130x over previous
//
#include <hip/hip_runtime.h>
#include <stdint.h>

typedef unsigned short u16;
typedef unsigned int   u32;

#define N_NODES  100000
#define N_EDGES  1600000
#define DFEAT    128
#define N_GRAPHS 512

#define NBKT   391    // buckets of 256 nodes (ceil(N/256))
#define EPB    8192   // edges per block in hist/scatter
#define NBLK_E 196    // ceil(N_EDGES/EPB)
#define LBUF   8192   // per-bucket capacity (mean 4096, sigma ~64)

typedef float f32x4 __attribute__((ext_vector_type(4)));
typedef short s16x8 __attribute__((ext_vector_type(8)));

__device__ __forceinline__ float bflo(u32 u) { return __uint_as_float(u << 16); }
__device__ __forceinline__ float bfhi(u32 u) { return __uint_as_float(u & 0xffff0000u); }
__device__ __forceinline__ u16 f2bf(float f) {
  u32 u = __float_as_uint(f);
  return (u16)((u + 0x7fffu + ((u >> 16) & 1u)) >> 16);   // RNE
}
__device__ __forceinline__ u32 pack2(float f0, float f1) {
  return (u32)f2bf(f0) | ((u32)f2bf(f1) << 16);
}

__device__ __forceinline__ int ld_src(const int* ei, int m, int e) {
  return m ? ei[2 * e] : ei[e];
}
__device__ __forceinline__ int ld_dst(const int* ei, int m, int e) {
  return m ? ei[2 * (N_EDGES + e)] : ei[N_EDGES + e];
}

// block-local int64-vs-int32 detect (odd words of first 64 edge slots all zero <=> int64)
__device__ __forceinline__ int detect_m_block(const int* __restrict__ ei, int* sm) {
  int t = threadIdx.x;
  if (t < 64) {
    int v = ei[2 * t + 1];
    unsigned long long b = __ballot(v != 0);
    if (t == 0) *sm = (b == 0ull) ? 1 : 0;
  }
  __syncthreads();
  return *sm;
}

// ---------------- pass A: per-block bucket histogram + W cvt + flag ----------------
__global__ __launch_bounds__(256) void histA_k(const int* __restrict__ ei,
                                               int* __restrict__ ghist,
                                               const float* __restrict__ W1,
                                               const float* __restrict__ W2,
                                               const float* __restrict__ W3,
                                               u16* __restrict__ T1, u16* __restrict__ T2,
                                               u16* __restrict__ T3, int* __restrict__ flag) {
  int t = threadIdx.x, b = blockIdx.x;
  if (b >= NBLK_E) {
    int r = b - NBLK_E;
    if (r < 3) {   // W transpose+convert
      const float* W = (r == 0) ? W1 : (r == 1) ? W2 : W3;
      u16* T         = (r == 0) ? T1 : (r == 1) ? T2 : T3;
      for (int i = t; i < DFEAT * DFEAT; i += 256) {
        int n = i >> 7, k = i & 127;
        T[i] = f2bf(W[k * DFEAT + n]);
      }
    } else {       // flag for pool_k
      if (t < 64) {
        int v = ei[2 * t + 1];
        unsigned long long mm = __ballot(v != 0);
        if (t == 0) *flag = (mm == 0ull) ? 1 : 0;
      }
    }
    return;
  }
  __shared__ int sm;
  __shared__ int hist[NBKT];
  int m = detect_m_block(ei, &sm);
  for (int i = t; i < NBKT; i += 256) hist[i] = 0;
  __syncthreads();
  int e0 = b * EPB;
#pragma unroll
  for (int p = 0; p < EPB / 256; p++) {
    int e = e0 + p * 256 + t;
    if (e < N_EDGES) atomicAdd(&hist[ld_dst(ei, m, e) >> 8], 1);
  }
  __syncthreads();
  for (int i = t; i < NBKT; i += 256) ghist[b * NBKT + i] = hist[i];
}

// ---------------- pass B: per-bucket exclusive scan over blocks ----------------
__global__ __launch_bounds__(256) void scanB1_k(int* __restrict__ ghist,
                                                int* __restrict__ gtot) {
  __shared__ int ts[256];
  int t = threadIdx.x, k = blockIdx.x;
  int v = (t < NBLK_E) ? ghist[t * NBKT + k] : 0;
  ts[t] = v;
  for (int off = 1; off < 256; off <<= 1) {
    __syncthreads(); int add = (t >= off) ? ts[t - off] : 0;
    __syncthreads(); ts[t] += add;
  }
  __syncthreads();
  if (t < NBLK_E) ghist[t * NBKT + k] = ts[t] - v;
  if (t == 255) gtot[k] = ts[255];
}

// in-block exclusive scan of gtot[NBKT] -> bb[NBKT+1]
__device__ __forceinline__ void scan_gtot_block(const int* __restrict__ gtot,
                                                int* bb, int* sc) {
  int t = threadIdx.x;
  int v0 = gtot[t];
  sc[t] = v0;
  for (int off = 1; off < 256; off <<= 1) {
    __syncthreads(); int add = (t >= off) ? sc[t - off] : 0;
    __syncthreads(); sc[t] += add;
  }
  __syncthreads();
  bb[t] = sc[t] - v0;
  int base256 = sc[255];
  __syncthreads();
  int v1 = (t < NBKT - 256) ? gtot[256 + t] : 0;
  sc[t] = v1;
  for (int off = 1; off < 256; off <<= 1) {
    __syncthreads(); int add = (t >= off) ? sc[t - off] : 0;
    __syncthreads(); sc[t] += add;
  }
  __syncthreads();
  if (t < NBKT - 256) bb[256 + t] = base256 + sc[t] - v1;
  if (t == 0) bb[NBKT] = N_EDGES;
  __syncthreads();
}

// ---------------- pass C: place edges into bucket regions ----------------
__global__ __launch_bounds__(256) void scatterC_k(const int* __restrict__ ei,
                                                  const int* __restrict__ obase,
                                                  const int* __restrict__ gtot,
                                                  u32* __restrict__ colpk) {
  __shared__ int sm;
  __shared__ int cur[NBKT];
  __shared__ int bb[NBKT + 1];
  __shared__ int sc[256];
  int t = threadIdx.x, b = blockIdx.x;
  int m = detect_m_block(ei, &sm);
  scan_gtot_block(gtot, bb, sc);
  for (int i = t; i < NBKT; i += 256) cur[i] = bb[i] + obase[b * NBKT + i];
  __syncthreads();
  int e0 = b * EPB;
#pragma unroll
  for (int p = 0; p < EPB / 256; p++) {
    int e = e0 + p * 256 + t;
    if (e < N_EDGES) {
      int d = ld_dst(ei, m, e);
      int s = ld_src(ei, m, e);
      int pos = atomicAdd(&cur[d >> 8], 1);
      colpk[pos] = (u32)s | ((u32)(d & 255) << 24);
    }
  }
}

// ---------------- pass D: degrees, rowptr, dinv, exact CSR placement ----------------
__global__ __launch_bounds__(256) void fillD_k(const int* __restrict__ gtot,
                                               const u32* __restrict__ colpk,
                                               int* __restrict__ colarr,
                                               int* __restrict__ rowptr,
                                               float* __restrict__ dinv) {
  __shared__ int hist[256];
  __shared__ int cur[256];
  __shared__ int lbuf[LBUF];
  __shared__ int bb[NBKT + 1];
  __shared__ int sc[256];
  int t = threadIdx.x, b = blockIdx.x;
  scan_gtot_block(gtot, bb, sc);
  int base = bb[b], end = bb[b + 1], cnt = end - base;
  hist[t] = 0;
  __syncthreads();
  for (int i = t; i < cnt; i += 256) atomicAdd(&hist[colpk[base + i] >> 24], 1);
  __syncthreads();
  int c = hist[t];
  cur[t] = c;
  for (int off = 1; off < 256; off <<= 1) {
    __syncthreads(); int add = (t >= off) ? cur[t - off] : 0;
    __syncthreads(); cur[t] += add;
  }
  __syncthreads();
  int excl = cur[t] - c;
  int node = b * 256 + t;
  if (node < N_NODES) {
    rowptr[node] = base + excl;
    dinv[node] = rsqrtf((float)(c + 1));      // +1 self-loop
  }
  if (b == NBKT - 1 && t == 0) rowptr[N_NODES] = N_EDGES;
  __syncthreads();
  cur[t] = excl;
  __syncthreads();
  for (int i = t; i < cnt; i += 256) {
    u32 v = colpk[base + i];
    int slot = atomicAdd(&cur[v >> 24], 1);
    if (slot < LBUF) lbuf[slot] = (int)(v & 0x00FFFFFFu);
  }
  __syncthreads();
  for (int i = t; i < cnt; i += 256) colarr[base + i] = lbuf[i];
}

// ---------------- MFMA GEMM: Y[r,:] = bf16((X @ W)[r,:] * dinv[r]) ----------------
// 128x128 tile; X input either f32 (converted during staging) or bf16.
#define LP 136   // LDS pitch in ushorts (272B, 16B-aligned rows)

__global__ __launch_bounds__(256, 1) void gemm_scale_k(const void* __restrict__ Xv,
                                                       int x_is_f32,
                                                       const u16* __restrict__ Wt,
                                                       const float* __restrict__ dinv,
                                                       u16* __restrict__ Y, int nrows) {
  __shared__ u16 sX[128 * LP];
  __shared__ u16 sW[128 * LP];
  int tid = threadIdx.x;
  int r0 = blockIdx.x * 128;

  for (int c = tid; c < 2048; c += 256) {
    int row = c >> 4, off = (c & 15) * 8;
    *(uint4*)(&sW[row * LP + off]) = *(const uint4*)(Wt + row * DFEAT + off);
  }
  if (x_is_f32) {
    const float* Xf = (const float*)Xv;
    for (int c = tid; c < 2048; c += 256) {
      int row = c >> 4, off = (c & 15) * 8;
      int grow = r0 + row;
      uint4 o = make_uint4(0, 0, 0, 0);
      if (grow < nrows) {
        const float* px = Xf + (size_t)grow * DFEAT + off;
        float4 v0 = *(const float4*)px;
        float4 v1 = *(const float4*)(px + 4);
        o.x = pack2(v0.x, v0.y); o.y = pack2(v0.z, v0.w);
        o.z = pack2(v1.x, v1.y); o.w = pack2(v1.z, v1.w);
      }
      *(uint4*)(&sX[row * LP + off]) = o;
    }
  } else {
    const u16* Xb = (const u16*)Xv;
    for (int c = tid; c < 2048; c += 256) {
      int row = c >> 4, off = (c & 15) * 8;
      int grow = r0 + row;
      uint4 v = make_uint4(0, 0, 0, 0);
      if (grow < nrows) v = *(const uint4*)(Xb + (size_t)grow * DFEAT + off);
      *(uint4*)(&sX[row * LP + off]) = v;
    }
  }
  __syncthreads();

  int wave = tid >> 6, lane = tid & 63;
  int q = lane >> 4, r = lane & 15;
  int wr0 = wave * 32;

  f32x4 acc[2][8];
#pragma unroll
  for (int m = 0; m < 2; m++)
#pragma unroll
    for (int i = 0; i < 8; i++) acc[m][i] = (f32x4){0.f, 0.f, 0.f, 0.f};

#pragma unroll
  for (int kk = 0; kk < 4; kk++) {
    int k0 = kk * 32;
    s16x8 a0 = *(const s16x8*)(&sX[(wr0 + r) * LP + k0 + q * 8]);
    s16x8 a1 = *(const s16x8*)(&sX[(wr0 + 16 + r) * LP + k0 + q * 8]);
#pragma unroll
    for (int nt = 0; nt < 8; nt++) {
      s16x8 b = *(const s16x8*)(&sW[(nt * 16 + r) * LP + k0 + q * 8]);
      acc[0][nt] = __builtin_amdgcn_mfma_f32_16x16x32_bf16(a0, b, acc[0][nt], 0, 0, 0);
      acc[1][nt] = __builtin_amdgcn_mfma_f32_16x16x32_bf16(a1, b, acc[1][nt], 0, 0, 0);
    }
  }

#pragma unroll
  for (int m = 0; m < 2; m++) {
#pragma unroll
    for (int i = 0; i < 4; i++) {
      int grow = r0 + wr0 + m * 16 + q * 4 + i;
      if (grow < nrows) {
        float dv = dinv[grow];
#pragma unroll
        for (int nt = 0; nt < 8; nt++) {
          Y[(size_t)grow * DFEAT + nt * 16 + r] = f2bf(acc[m][nt][i] * dv);
        }
      }
    }
  }
}

// ---------------- aggregation (bf16 rows, f32 accumulate) ----------------
struct Acc8 {
  float a0, a1, a2, a3, a4, a5, a6, a7;
  __device__ __forceinline__ void add(uint4 v) {
    a0 += bflo(v.x); a1 += bfhi(v.x); a2 += bflo(v.y); a3 += bfhi(v.y);
    a4 += bflo(v.z); a5 += bfhi(v.z); a6 += bflo(v.w); a7 += bfhi(v.w);
  }
};

__global__ __launch_bounds__(256) void agg_k(const u32* __restrict__ HS,
                                             const float* __restrict__ dinv,
                                             const int* __restrict__ rowptr,
                                             const int* __restrict__ colidx,
                                             const float* __restrict__ bias,
                                             u32* __restrict__ OUT, int do_relu) {
  int t = threadIdx.x;
  int node = blockIdx.x * 16 + (t >> 4);   // grid 6250 -> exactly N_NODES
  int fp = t & 15;

  int s = rowptr[node], e = rowptr[node + 1];

  Acc8 A;
  uint4 v = *(const uint4*)(HS + (size_t)node * 64 + fp * 4);   // self row
  A.a0 = bflo(v.x); A.a1 = bfhi(v.x); A.a2 = bflo(v.y); A.a3 = bfhi(v.y);
  A.a4 = bflo(v.z); A.a5 = bfhi(v.z); A.a6 = bflo(v.w); A.a7 = bfhi(v.w);

  int j = s;
  for (; j + 4 <= e; j += 4) {
    int i0 = colidx[j], i1 = colidx[j + 1], i2 = colidx[j + 2], i3 = colidx[j + 3];
    uint4 w0 = *(const uint4*)(HS + (size_t)i0 * 64 + fp * 4);
    uint4 w1 = *(const uint4*)(HS + (size_t)i1 * 64 + fp * 4);
    uint4 w2 = *(const uint4*)(HS + (size_t)i2 * 64 + fp * 4);
    uint4 w3 = *(const uint4*)(HS + (size_t)i3 * 64 + fp * 4);
    A.add(w0); A.add(w1); A.add(w2); A.add(w3);
  }
  for (; j < e; j++) {
    int i0 = colidx[j];
    uint4 w0 = *(const uint4*)(HS + (size_t)i0 * 64 + fp * 4);
    A.add(w0);
  }

  float dv = dinv[node];
  float4 b0 = *(const float4*)(bias + fp * 8);
  float4 b1 = *(const float4*)(bias + fp * 8 + 4);
  float r0 = A.a0 * dv + b0.x, r1 = A.a1 * dv + b0.y;
  float r2 = A.a2 * dv + b0.z, r3 = A.a3 * dv + b0.w;
  float r4 = A.a4 * dv + b1.x, r5 = A.a5 * dv + b1.y;
  float r6 = A.a6 * dv + b1.z, r7 = A.a7 * dv + b1.w;
  if (do_relu) {
    r0 = fmaxf(r0, 0.f); r1 = fmaxf(r1, 0.f); r2 = fmaxf(r2, 0.f); r3 = fmaxf(r3, 0.f);
    r4 = fmaxf(r4, 0.f); r5 = fmaxf(r5, 0.f); r6 = fmaxf(r6, 0.f); r7 = fmaxf(r7, 0.f);
  }
  uint4 o;
  o.x = pack2(r0, r1); o.y = pack2(r2, r3); o.z = pack2(r4, r5); o.w = pack2(r6, r7);
  *(uint4*)(OUT + (size_t)node * 64 + fp * 4) = o;
}

// ---------------- pooling: mean over sorted batch ranges ----------------
__device__ __forceinline__ int lower_bound_i(const int* a, int n, int key, int shift) {
  int lo = 0, hi = n;
  while (lo < hi) {
    int mid = (lo + hi) >> 1;
    if (a[mid << shift] < key) lo = mid + 1; else hi = mid;
  }
  return lo;
}

__global__ __launch_bounds__(256) void pool_k(const u32* __restrict__ H,
                                              const int* __restrict__ batch,
                                              const int* __restrict__ flag,
                                              float* __restrict__ OUT) {
  int g = blockIdx.x;
  int m = *flag;   // 1 if int64 batch
  int lo = lower_bound_i(batch, N_NODES, g, m);
  int hi = lower_bound_i(batch, N_NODES, g + 1, m);
  int cnt = hi - lo;
  int d2 = threadIdx.x & 63;
  int half = threadIdx.x >> 6;
  float a0 = 0.f, a1 = 0.f;
  for (int row = lo + half; row < hi; row += 4) {
    u32 v = H[(size_t)row * 64 + d2];
    a0 += bflo(v); a1 += bfhi(v);
  }
  __shared__ float red0[256], red1[256];
  red0[threadIdx.x] = a0; red1[threadIdx.x] = a1;
  __syncthreads();
  if (threadIdx.x < 64) {
    float s0 = red0[d2] + red0[d2 + 64] + red0[d2 + 128] + red0[d2 + 192];
    float s1 = red1[d2] + red1[d2 + 64] + red1[d2 + 128] + red1[d2 + 192];
    float inv = 1.0f / fmaxf((float)cnt, 1.0f);
    OUT[g * DFEAT + 2 * d2]     = s0 * inv;
    OUT[g * DFEAT + 2 * d2 + 1] = s1 * inv;
  }
}

// ---------------- orchestration ----------------

extern "C" void kernel_launch(void* const* d_in, const int* in_sizes, int n_in,
                              void* d_out, int out_size, void* d_ws, size_t ws_size,
                              hipStream_t stream) {
  const float* x   = (const float*)d_in[0];
  const int* ei    = (const int*)d_in[1];
  const int* batch = (const int*)d_in[2];
  const float* W1  = (const float*)d_in[3];
  const float* b1  = (const float*)d_in[4];
  const float* W2  = (const float*)d_in[5];
  const float* b2  = (const float*)d_in[6];
  const float* W3  = (const float*)d_in[7];
  const float* b3  = (const float*)d_in[8];
  float* out = (float*)d_out;

  char* p = (char*)d_ws;
  size_t off = 0;
  auto carve = [&](size_t bytes) -> void* {
    void* q = p + off;
    off = (off + bytes + 255) & ~(size_t)255;
    return q;
  };
  int*   flag   = (int*)carve(256);
  int*   ghist  = (int*)carve((size_t)NBLK_E * NBKT * 4);   // becomes obase in-place
  int*   gtot   = (int*)carve(NBKT * 4);
  int*   rowptr = (int*)carve((N_NODES + 1) * 4);
  float* dinv   = (float*)carve(N_NODES * 4);
  u32*   colpk  = (u32*)carve((size_t)N_EDGES * 4);
  int*   colarr = (int*)carve((size_t)N_EDGES * 4);
  u16*   Wt1    = (u16*)carve(DFEAT * DFEAT * 2);
  u16*   Wt2    = (u16*)carve(DFEAT * DFEAT * 2);
  u16*   Wt3    = (u16*)carve(DFEAT * DFEAT * 2);
  u32*   bufA   = (u32*)carve((size_t)N_NODES * 64 * 4);
  u32*   bufB   = (u32*)carve((size_t)N_NODES * 64 * 4);
  (void)ws_size;

  histA_k<<<NBLK_E + 4, 256, 0, stream>>>(ei, ghist, W1, W2, W3, Wt1, Wt2, Wt3, flag);
  scanB1_k<<<NBKT, 256, 0, stream>>>(ghist, gtot);
  scatterC_k<<<NBLK_E, 256, 0, stream>>>(ei, ghist, gtot, colpk);
  fillD_k<<<NBKT, 256, 0, stream>>>(gtot, colpk, colarr, rowptr, dinv);

  const int GB = (N_NODES + 127) / 128;   // 782
  const int AB = N_NODES / 16;            // 6250

  gemm_scale_k<<<GB, 256, 0, stream>>>((const void*)x, 1, Wt1, dinv, (u16*)bufA, N_NODES);
  agg_k<<<AB, 256, 0, stream>>>(bufA, dinv, rowptr, colarr, b1, bufB, 1);
  gemm_scale_k<<<GB, 256, 0, stream>>>((const void*)bufB, 0, Wt2, dinv, (u16*)bufA, N_NODES);
  agg_k<<<AB, 256, 0, stream>>>(bufA, dinv, rowptr, colarr, b2, bufB, 1);
  gemm_scale_k<<<GB, 256, 0, stream>>>((const void*)bufB, 0, Wt3, dinv, (u16*)bufA, N_NODES);
  agg_k<<<AB, 256, 0, stream>>>(bufA, dinv, rowptr, colarr, b3, bufB, 0);
  pool_k<<<N_GRAPHS, 256, 0, stream>>>(bufB, batch, flag, out);
}